// Round 1
// baseline (2186.618 us; speedup 1.0000x reference)
//
#include <hip/hip_runtime.h>
#include <stdint.h>

#define NBATCH 8
#define NA 262144
#define KTOP 6000
#define PROP 1000
#define NCAND 8192
#define NBINS 4096
#define NMS_THR 0.7f
#define NW 188   // ceil(6000/32) = 188 (187*32=5984, +16 bits)

static constexpr size_t OFF_HIST  = 0;                                   // NBATCH*NBINS*4 = 131072
static constexpr size_t OFF_CNT   = 131072;                              // NBATCH*4
static constexpr size_t OFF_CUT   = 131104;                              // NBATCH*4
static constexpr size_t OFF_CAND  = 131584;                              // NBATCH*NCAND*8 = 524288
static constexpr size_t OFF_BOXES = OFF_CAND + (size_t)NBATCH*NCAND*8;   // 655872 (16B aligned)

// ---------------- Pass 1: per-batch 4096-bin linear histogram of scores ----------------
__global__ __launch_bounds__(256) void hist_kernel(const float2* __restrict__ probs,
                                                   unsigned int* __restrict__ hist) {
    __shared__ unsigned int h[NBINS];
    const int b = blockIdx.y;
    for (int i = threadIdx.x; i < NBINS; i += 256) h[i] = 0;
    __syncthreads();
    const float2* p = probs + (size_t)b * NA;
    const int base = blockIdx.x * 2048;
    for (int k = 0; k < 8; ++k) {
        int a = base + k * 256 + threadIdx.x;
        float s = p[a].y;                       // rpn_probs[b][a][1]
        int bin = (int)(s * (float)NBINS);
        bin = bin < 0 ? 0 : (bin > NBINS - 1 ? NBINS - 1 : bin);
        atomicAdd(&h[bin], 1u);
    }
    __syncthreads();
    unsigned int* gh = hist + (size_t)b * NBINS;
    for (int i = threadIdx.x; i < NBINS; i += 256) {
        unsigned int v = h[i];
        if (v) atomicAdd(&gh[i], v);
    }
}

// ---------------- Pass 2: find cutoff bin (cum from top >= KTOP) ----------------
__global__ void cutoff_kernel(const unsigned int* __restrict__ hist,
                              unsigned int* __restrict__ cut) {
    const int b = blockIdx.x;
    if (threadIdx.x == 0) {
        const unsigned int* h = hist + (size_t)b * NBINS;
        unsigned int cum = 0; int binsel = 0;
        for (int i = NBINS - 1; i >= 0; --i) {
            cum += h[i];
            if (cum >= KTOP) { binsel = i; break; }
        }
        cut[b] = (unsigned int)binsel;
    }
}

// ---------------- Pass 3: compact candidates (key = score_bits<<32 | ~index) ----------------
__global__ __launch_bounds__(256) void compact_kernel(const float2* __restrict__ probs,
                                                      const unsigned int* __restrict__ cut,
                                                      unsigned int* __restrict__ cnt,
                                                      unsigned long long* __restrict__ cand) {
    const int b = blockIdx.y;
    const int a = blockIdx.x * 256 + threadIdx.x;
    float s = probs[(size_t)b * NA + a].y;
    int bin = (int)(s * (float)NBINS);
    bin = bin < 0 ? 0 : (bin > NBINS - 1 ? NBINS - 1 : bin);
    if ((unsigned int)bin >= cut[b]) {
        unsigned int pos = atomicAdd(&cnt[b], 1u);
        if (pos < NCAND) {
            unsigned long long key =
                ((unsigned long long)__float_as_uint(s) << 32) | (unsigned int)(~a);
            cand[(size_t)b * NCAND + pos] = key;
        }
    }
}

// ---------------- Pass 4: bitonic sort (desc) + gather + box decode ----------------
__global__ __launch_bounds__(1024) void sort_box_kernel(const unsigned long long* __restrict__ cand,
                                                        const unsigned int* __restrict__ cnt,
                                                        const float4* __restrict__ anchors,
                                                        const float4* __restrict__ bbox,
                                                        float4* __restrict__ boxes) {
    extern __shared__ unsigned long long keys[];  // NCAND entries
    const int b = blockIdx.x;
    unsigned int n = cnt[b]; if (n > NCAND) n = NCAND;
    const unsigned long long* cb = cand + (size_t)b * NCAND;
    for (int i = threadIdx.x; i < NCAND; i += 1024)
        keys[i] = (i < (int)n) ? cb[i] : 0ull;    // key 0 sorts last (desc)
    __syncthreads();
    for (int k = 2; k <= NCAND; k <<= 1) {
        for (int j = k >> 1; j > 0; j >>= 1) {
            for (int i = threadIdx.x; i < NCAND; i += 1024) {
                int ixj = i ^ j;
                if (ixj > i) {
                    unsigned long long a0 = keys[i], a1 = keys[ixj];
                    bool desc = (i & k) == 0;
                    if (desc ? (a0 < a1) : (a0 > a1)) { keys[i] = a1; keys[ixj] = a0; }
                }
            }
            __syncthreads();
        }
    }
    for (int r = threadIdx.x; r < KTOP; r += 1024) {
        unsigned long long e = keys[r];
        unsigned int idx = ~(unsigned int)(e & 0xFFFFFFFFull);
        float4 anc = anchors[(size_t)b * NA + idx];
        float4 del = bbox[(size_t)b * NA + idx];
        float dy = del.x * 0.1f, dx = del.y * 0.1f, dh = del.z * 0.2f, dw = del.w * 0.2f;
        float h = anc.z - anc.x, w = anc.w - anc.y;
        float cy = anc.x + 0.5f * h + dy * h;
        float cx = anc.y + 0.5f * w + dx * w;
        h = h * expf(dh);
        w = w * expf(dw);
        float y1v = fminf(fmaxf(cy - 0.5f * h, 0.f), 1.f);
        float x1v = fminf(fmaxf(cx - 0.5f * w, 0.f), 1.f);
        float y2v = fminf(fmaxf(cy + 0.5f * h, 0.f), 1.f);
        float x2v = fminf(fmaxf(cx + 0.5f * w, 0.f), 1.f);
        boxes[(size_t)b * KTOP + r] = make_float4(y1v, x1v, y2v, x2v);
    }
}

// ---------------- Pass 5: greedy NMS, one workgroup per batch ----------------
__global__ __launch_bounds__(1024) void nms_kernel(const float4* __restrict__ boxes,
                                                   float* __restrict__ out) {
    extern __shared__ float sm[];
    float* sy1 = sm;
    float* sx1 = sy1 + KTOP;
    float* sy2 = sx1 + KTOP;
    float* sx2 = sy2 + KTOP;
    float* sar = sx2 + KTOP;
    unsigned int* vw = (unsigned int*)(sar + KTOP);
    int* ctrl = (int*)(vw + NW);
    const int b = blockIdx.x;
    const int tid = threadIdx.x;

    for (int r = tid; r < KTOP; r += 1024) {
        float4 v = boxes[(size_t)b * KTOP + r];
        sy1[r] = v.x; sx1[r] = v.y; sy2[r] = v.z; sx2[r] = v.w;
        sar[r] = (v.z - v.x) * (v.w - v.y);
    }
    for (int i = tid; i < NW; i += 1024)
        vw[i] = (i < NW - 1) ? 0xFFFFFFFFu : 0x0000FFFFu;  // 5984 + 16 = 6000 bits
    __syncthreads();

    int wf = 0;          // front word pointer (thread 0 only)
    int done = PROP;
    for (int it = 0; it < PROP; ++it) {
        if (tid == 0) {
            int cur = -1;
            while (wf < NW) {
                unsigned int w = vw[wf];
                if (w) {
                    int bit = __ffs(w) - 1;
                    cur = (wf << 5) + bit;
                    vw[wf] = w & ~(1u << bit);   // remove selected
                    break;
                }
                ++wf;
            }
            *ctrl = cur;
        }
        __syncthreads();
        int cur = *ctrl;
        if (cur < 0) { done = it; break; }

        float by1 = sy1[cur], bx1 = sx1[cur], by2 = sy2[cur], bx2 = sx2[cur];
        float barea = sar[cur];
        for (int j = cur + 1 + tid; j < KTOP; j += 1024) {
            unsigned int word = vw[j >> 5];
            if (word & (1u << (j & 31))) {
                float yy1 = fmaxf(by1, sy1[j]);
                float xx1 = fmaxf(bx1, sx1[j]);
                float yy2 = fminf(by2, sy2[j]);
                float xx2 = fminf(bx2, sx2[j]);
                float inter = fmaxf(yy2 - yy1, 0.f) * fmaxf(xx2 - xx1, 0.f);
                float uni = barea + sar[j] - inter;
                float iou = inter / fmaxf(uni, 1e-12f);
                if (iou > NMS_THR)
                    atomicAnd(&vw[j >> 5], ~(1u << (j & 31)));
            }
        }
        if (tid < 4) {
            float comp = (tid == 0) ? by1 : (tid == 1) ? bx1 : (tid == 2) ? by2 : bx2;
            out[((size_t)b * PROP + it) * 4 + tid] = comp;
        }
        __syncthreads();
    }
    // zero-fill tail if we ran out of valid boxes (matches reference any_valid path)
    for (int i = done * 4 + tid; i < PROP * 4; i += 1024)
        out[(size_t)b * PROP * 4 + i] = 0.f;
}

extern "C" void kernel_launch(void* const* d_in, const int* in_sizes, int n_in,
                              void* d_out, int out_size, void* d_ws, size_t ws_size,
                              hipStream_t stream) {
    const float2* probs   = (const float2*)d_in[0];
    const float4* bbox    = (const float4*)d_in[1];
    const float4* anchors = (const float4*)d_in[2];
    char* ws = (char*)d_ws;
    unsigned int* hist       = (unsigned int*)(ws + OFF_HIST);
    unsigned int* cnt        = (unsigned int*)(ws + OFF_CNT);
    unsigned int* cut        = (unsigned int*)(ws + OFF_CUT);
    unsigned long long* cand = (unsigned long long*)(ws + OFF_CAND);
    float4* boxes            = (float4*)(ws + OFF_BOXES);
    float* out = (float*)d_out;

    // zero hist + cnt each call (graph-capture safe)
    hipMemsetAsync(d_ws, 0, OFF_CUT, stream);

    hist_kernel<<<dim3(NA / 2048, NBATCH), 256, 0, stream>>>(probs, hist);
    cutoff_kernel<<<dim3(NBATCH), 64, 0, stream>>>(hist, cut);
    compact_kernel<<<dim3(NA / 256, NBATCH), 256, 0, stream>>>(probs, cut, cnt, cand);
    sort_box_kernel<<<dim3(NBATCH), 1024, NCAND * 8, stream>>>(cand, cnt, anchors, bbox, boxes);
    size_t nms_lds = (size_t)5 * KTOP * 4 + NW * 4 + 16;   // 120768 bytes
    nms_kernel<<<dim3(NBATCH), 1024, nms_lds, stream>>>(boxes, out);
}

// Round 2
// 817.351 us; speedup vs baseline: 2.6753x; 2.6753x over previous
//
#include <hip/hip_runtime.h>
#include <stdint.h>

#define NBATCH 8
#define NA 262144
#define KTOP 6000
#define PROP 1000
#define NCAND 8192
#define NBINS 4096
#define NMS_THR 0.7f
#define NPAD 6016          // KTOP padded to 94*64
#define MCH 94             // u64 chunks per mask row
#define NW32 188           // ceil(6000/32)

// ---- workspace layout (bytes) ----
static constexpr size_t OFF_HIST   = 0;                       // 8*4096*4 = 131072
static constexpr size_t OFF_CNT    = 131072;                  // 32
static constexpr size_t OFF_ROWANY = 131104;                  // 8*192*4 = 6144
static constexpr size_t ZERO_BYTES = 137248;                  // hist+cnt+rowany
static constexpr size_t OFF_CUT    = 137248;                  // 32
static constexpr size_t OFF_CAND   = 137280;                  // 8*8192*8 = 524288
static constexpr size_t OFF_BOXESP = 661568;                  // 8*6016*16 = 770048
static constexpr size_t OFF_MASK   = 1431616;                 // 8*94*6016*8 = 36192256
static constexpr size_t NEEDED     = OFF_MASK + (size_t)NBATCH * MCH * NPAD * 8; // 37623872
static constexpr size_t NEEDED_FB  = OFF_MASK;                // fallback path

// ---------------- Pass 1: per-batch 4096-bin linear histogram ----------------
__global__ __launch_bounds__(256) void hist_kernel(const float2* __restrict__ probs,
                                                   unsigned int* __restrict__ hist) {
    __shared__ unsigned int h[NBINS];
    const int b = blockIdx.y;
    for (int i = threadIdx.x; i < NBINS; i += 256) h[i] = 0;
    __syncthreads();
    const float2* p = probs + (size_t)b * NA;
    const int base = blockIdx.x * 2048;
    for (int k = 0; k < 8; ++k) {
        int a = base + k * 256 + threadIdx.x;
        float s = p[a].y;
        int bin = (int)(s * (float)NBINS);
        bin = bin < 0 ? 0 : (bin > NBINS - 1 ? NBINS - 1 : bin);
        atomicAdd(&h[bin], 1u);
    }
    __syncthreads();
    unsigned int* gh = hist + (size_t)b * NBINS;
    for (int i = threadIdx.x; i < NBINS; i += 256) {
        unsigned int v = h[i];
        if (v) atomicAdd(&gh[i], v);
    }
}

// ---------------- Pass 2: cutoff bin, wave-parallel suffix scan ----------------
__global__ __launch_bounds__(64) void cutoff_kernel(const unsigned int* __restrict__ hist,
                                                    unsigned int* __restrict__ cut) {
    const int b = blockIdx.x;
    const int l = threadIdx.x;
    const unsigned int* h = hist + (size_t)b * NBINS;
    // chunk sums: lane l owns bins [l*64, l*64+64)
    unsigned int s = 0;
    for (int k = 0; k < 64; ++k) s += h[l * 64 + k];
    // suffix sum C[l] = sum_{c>=l} S[c]
    unsigned int c = s;
    for (int off = 1; off < 64; off <<= 1) {
        unsigned int v = __shfl_down(c, off);
        if (l + off < 64) c += v;
    }
    unsigned long long ball = __ballot(c >= (unsigned)KTOP);
    int csel = 63 - __builtin_clzll(ball);          // largest lane with C >= KTOP
    unsigned int cnext = (csel < 63) ? __shfl(c, csel + 1) : 0u;
    unsigned int rem = (unsigned)KTOP - cnext;      // needed from chunk csel (>=1)
    // phase 2: bins of chunk csel
    unsigned int v2 = h[csel * 64 + l];
    unsigned int c2 = v2;
    for (int off = 1; off < 64; off <<= 1) {
        unsigned int v = __shfl_down(c2, off);
        if (l + off < 64) c2 += v;
    }
    unsigned long long ball2 = __ballot(c2 >= rem);
    int bsel = 63 - __builtin_clzll(ball2);
    if (l == 0) cut[b] = (unsigned int)(csel * 64 + bsel);
}

// ---------------- Pass 3: compact candidates ----------------
__global__ __launch_bounds__(256) void compact_kernel(const float2* __restrict__ probs,
                                                      const unsigned int* __restrict__ cut,
                                                      unsigned int* __restrict__ cnt,
                                                      unsigned long long* __restrict__ cand) {
    const int b = blockIdx.y;
    const int a = blockIdx.x * 256 + threadIdx.x;
    float s = probs[(size_t)b * NA + a].y;
    int bin = (int)(s * (float)NBINS);
    bin = bin < 0 ? 0 : (bin > NBINS - 1 ? NBINS - 1 : bin);
    if ((unsigned int)bin >= cut[b]) {
        unsigned int pos = atomicAdd(&cnt[b], 1u);
        if (pos < NCAND) {
            unsigned long long key =
                ((unsigned long long)__float_as_uint(s) << 32) | (unsigned int)(~a);
            cand[(size_t)b * NCAND + pos] = key;
        }
    }
}

// ---------------- Pass 4: bitonic sort (desc) + gather + box decode ----------------
__global__ __launch_bounds__(512) void sort_box_kernel(const unsigned long long* __restrict__ cand,
                                                       const unsigned int* __restrict__ cnt,
                                                       const float4* __restrict__ anchors,
                                                       const float4* __restrict__ bbox,
                                                       float4* __restrict__ boxesP) {
    extern __shared__ unsigned long long keys[];  // NCAND
    const int b = blockIdx.x;
    unsigned int n = cnt[b]; if (n > NCAND) n = NCAND;
    const unsigned long long* cb = cand + (size_t)b * NCAND;
    for (int i = threadIdx.x; i < NCAND; i += 512)
        keys[i] = (i < (int)n) ? cb[i] : 0ull;
    __syncthreads();
    for (int k = 2; k <= NCAND; k <<= 1) {
        for (int j = k >> 1; j > 0; j >>= 1) {
            for (int i = threadIdx.x; i < NCAND; i += 512) {
                int ixj = i ^ j;
                if (ixj > i) {
                    unsigned long long a0 = keys[i], a1 = keys[ixj];
                    bool desc = (i & k) == 0;
                    if (desc ? (a0 < a1) : (a0 > a1)) { keys[i] = a1; keys[ixj] = a0; }
                }
            }
            __syncthreads();
        }
    }
    for (int r = threadIdx.x; r < KTOP; r += 512) {
        unsigned long long e = keys[r];
        unsigned int idx = ~(unsigned int)(e & 0xFFFFFFFFull);
        float4 anc = anchors[(size_t)b * NA + idx];
        float4 del = bbox[(size_t)b * NA + idx];
        float dy = del.x * 0.1f, dx = del.y * 0.1f, dh = del.z * 0.2f, dw = del.w * 0.2f;
        float h = anc.z - anc.x, w = anc.w - anc.y;
        float cy = anc.x + 0.5f * h + dy * h;
        float cx = anc.y + 0.5f * w + dx * w;
        h = h * expf(dh);
        w = w * expf(dw);
        float y1v = fminf(fmaxf(cy - 0.5f * h, 0.f), 1.f);
        float x1v = fminf(fmaxf(cx - 0.5f * w, 0.f), 1.f);
        float y2v = fminf(fmaxf(cy + 0.5f * h, 0.f), 1.f);
        float x2v = fminf(fmaxf(cx + 0.5f * w, 0.f), 1.f);
        boxesP[(size_t)b * NPAD + r] = make_float4(y1v, x1v, y2v, x2v);
    }
    for (int r = KTOP + threadIdx.x; r < NPAD; r += 512)
        boxesP[(size_t)b * NPAD + r] = make_float4(0.f, 0.f, 0.f, 0.f);
}

// ---------------- Pass 5a: IoU suppression bit-matrix ----------------
// mask[(b*MCH + cx)*NPAD + i] : 64-bit chunk, bit j set iff IoU(box_i, box_{cx*64+j}) > thr && cx*64+j > i
__global__ __launch_bounds__(256) void mask_kernel(const float4* __restrict__ boxesP,
                                                   unsigned long long* __restrict__ mask,
                                                   unsigned int* __restrict__ rowany) {
    const int bx = blockIdx.x;          // group of 4 col chunks
    const int cy = blockIdx.y;          // row chunk
    const int b  = blockIdx.z;
    if (bx * 4 + 3 < cy) return;        // whole block below diagonal
    const int t  = threadIdx.x;
    __shared__ float4 cbx[256];
    __shared__ float  car[256];
    int cj = bx * 256 + t;
    float4 c4 = (cj < NPAD) ? boxesP[(size_t)b * NPAD + cj] : make_float4(0.f,0.f,0.f,0.f);
    cbx[t] = c4;
    car[t] = (c4.z - c4.x) * (c4.w - c4.y);
    __syncthreads();
    const int cx = bx * 4 + (t >> 6);
    const int tl = t & 63;
    if (cx >= MCH || cx < cy) return;
    const int i = cy * 64 + tl;
    float4 r4 = boxesP[(size_t)b * NPAD + i];
    float rar = (r4.z - r4.x) * (r4.w - r4.y);
    const int cb0 = (t >> 6) * 64;
    unsigned long long m = 0ull;
    #pragma unroll 8
    for (int j = 0; j < 64; ++j) {
        float4 q = cbx[cb0 + j];
        float yy1 = fmaxf(r4.x, q.x), xx1 = fmaxf(r4.y, q.y);
        float yy2 = fminf(r4.z, q.z), xx2 = fminf(r4.w, q.w);
        float inter = fmaxf(yy2 - yy1, 0.f) * fmaxf(xx2 - xx1, 0.f);
        float uni = rar + car[cb0 + j] - inter;
        float iou = inter / fmaxf(uni, 1e-12f);     // IEEE div to match np reference
        m |= ((unsigned long long)(iou > NMS_THR)) << j;
    }
    unsigned long long allow = (cx > cy) ? ~0ull : ((tl == 63) ? 0ull : (~0ull << (tl + 1)));
    m &= allow;
    mask[((size_t)(b * MCH + cx)) * NPAD + i] = m;
    if (m) atomicOr(&rowany[b * 192 + (i >> 5)], 1u << (i & 31));
}

// ---------------- Pass 5b: serial walk, 1 wave per batch ----------------
__global__ __launch_bounds__(64) void walk_kernel(const float4* __restrict__ boxesP,
                                                  const unsigned long long* __restrict__ mask,
                                                  const unsigned int* __restrict__ rowany,
                                                  float4* __restrict__ out) {
    __shared__ unsigned long long removed64[96];
    __shared__ unsigned int rany[192];
    __shared__ unsigned int outIdx[PROP];
    unsigned int* removed32 = (unsigned int*)removed64;
    const int b = blockIdx.x;
    const int t = threadIdx.x;
    removed32[t] = 0u;
    removed32[t + 64] = 0u;
    removed32[t + 128] = (t + 128 == 187) ? 0xFFFF0000u : 0u;  // bits 6000..6015 invalid
    rany[t]       = rowany[b * 192 + t];
    rany[t + 64]  = rowany[b * 192 + 64 + t];
    rany[t + 128] = rowany[b * 192 + 128 + t];
    __syncthreads();

    int sel = 0;
    for (int w = 0; w < NW32 && sel < PROP; ++w) {
        unsigned int avail = ~removed32[w];
        while (avail && sel < PROP) {
            int bit = __ffs(avail) - 1;
            avail &= avail - 1u;
            int i = (w << 5) + bit;
            if (t == 0) outIdx[sel] = (unsigned int)i;
            ++sel;
            if ((rany[w] >> bit) & 1u) {
                // OR row i into removed (64-lane parallel)
                const unsigned long long* rowp = mask + (size_t)b * MCH * NPAD + i;
                unsigned long long v0 = rowp[(size_t)t * NPAD];
                removed64[t] |= v0;
                if (t < MCH - 64) {
                    unsigned long long v1 = rowp[(size_t)(t + 64) * NPAD];
                    removed64[t + 64] |= v1;
                }
                __syncthreads();
                avail &= ~removed32[w];   // new suppressions within current word
            }
        }
    }
    __syncthreads();
    float4* ob = out + (size_t)b * PROP;
    for (int k = t; k < PROP; k += 64) {
        float4 v = (k < sel) ? boxesP[(size_t)b * NPAD + outIdx[k]]
                             : make_float4(0.f, 0.f, 0.f, 0.f);
        ob[k] = v;
    }
}

// ---------------- Fallback: round-1 serial NMS (if ws too small) ----------------
__global__ __launch_bounds__(1024) void nms_fallback_kernel(const float4* __restrict__ boxesP,
                                                            float* __restrict__ out) {
    extern __shared__ float sm[];
    float* sy1 = sm;
    float* sx1 = sy1 + KTOP;
    float* sy2 = sx1 + KTOP;
    float* sx2 = sy2 + KTOP;
    float* sar = sx2 + KTOP;
    unsigned int* vw = (unsigned int*)(sar + KTOP);
    int* ctrl = (int*)(vw + NW32);
    const int b = blockIdx.x;
    const int tid = threadIdx.x;
    for (int r = tid; r < KTOP; r += 1024) {
        float4 v = boxesP[(size_t)b * NPAD + r];
        sy1[r] = v.x; sx1[r] = v.y; sy2[r] = v.z; sx2[r] = v.w;
        sar[r] = (v.z - v.x) * (v.w - v.y);
    }
    for (int i = tid; i < NW32; i += 1024)
        vw[i] = (i < NW32 - 1) ? 0xFFFFFFFFu : 0x0000FFFFu;
    __syncthreads();
    int wf = 0;
    int done = PROP;
    for (int it = 0; it < PROP; ++it) {
        if (tid == 0) {
            int cur = -1;
            while (wf < NW32) {
                unsigned int w = vw[wf];
                if (w) { int bit = __ffs(w) - 1; cur = (wf << 5) + bit; vw[wf] = w & ~(1u << bit); break; }
                ++wf;
            }
            *ctrl = cur;
        }
        __syncthreads();
        int cur = *ctrl;
        if (cur < 0) { done = it; break; }
        float by1 = sy1[cur], bx1 = sx1[cur], by2 = sy2[cur], bx2 = sx2[cur];
        float barea = sar[cur];
        for (int j = cur + 1 + tid; j < KTOP; j += 1024) {
            unsigned int word = vw[j >> 5];
            if (word & (1u << (j & 31))) {
                float yy1 = fmaxf(by1, sy1[j]);
                float xx1 = fmaxf(bx1, sx1[j]);
                float yy2 = fminf(by2, sy2[j]);
                float xx2 = fminf(bx2, sx2[j]);
                float inter = fmaxf(yy2 - yy1, 0.f) * fmaxf(xx2 - xx1, 0.f);
                float uni = barea + sar[j] - inter;
                float iou = inter / fmaxf(uni, 1e-12f);
                if (iou > NMS_THR) atomicAnd(&vw[j >> 5], ~(1u << (j & 31)));
            }
        }
        if (tid < 4) {
            float comp = (tid == 0) ? by1 : (tid == 1) ? bx1 : (tid == 2) ? by2 : bx2;
            out[((size_t)b * PROP + it) * 4 + tid] = comp;
        }
        __syncthreads();
    }
    for (int i = done * 4 + tid; i < PROP * 4; i += 1024)
        out[(size_t)b * PROP * 4 + i] = 0.f;
}

extern "C" void kernel_launch(void* const* d_in, const int* in_sizes, int n_in,
                              void* d_out, int out_size, void* d_ws, size_t ws_size,
                              hipStream_t stream) {
    const float2* probs   = (const float2*)d_in[0];
    const float4* bbox    = (const float4*)d_in[1];
    const float4* anchors = (const float4*)d_in[2];
    char* ws = (char*)d_ws;
    unsigned int* hist        = (unsigned int*)(ws + OFF_HIST);
    unsigned int* cnt         = (unsigned int*)(ws + OFF_CNT);
    unsigned int* rowany      = (unsigned int*)(ws + OFF_ROWANY);
    unsigned int* cut         = (unsigned int*)(ws + OFF_CUT);
    unsigned long long* cand  = (unsigned long long*)(ws + OFF_CAND);
    float4* boxesP            = (float4*)(ws + OFF_BOXESP);
    unsigned long long* mask  = (unsigned long long*)(ws + OFF_MASK);
    float4* out = (float4*)d_out;

    hipMemsetAsync(d_ws, 0, ZERO_BYTES, stream);   // hist + cnt + rowany

    hist_kernel<<<dim3(NA / 2048, NBATCH), 256, 0, stream>>>(probs, hist);
    cutoff_kernel<<<dim3(NBATCH), 64, 0, stream>>>(hist, cut);
    compact_kernel<<<dim3(NA / 256, NBATCH), 256, 0, stream>>>(probs, cut, cnt, cand);
    sort_box_kernel<<<dim3(NBATCH), 512, NCAND * 8, stream>>>(cand, cnt, anchors, bbox, boxesP);

    if (ws_size >= NEEDED) {
        mask_kernel<<<dim3((MCH + 3) / 4, MCH, NBATCH), 256, 0, stream>>>(boxesP, mask, rowany);
        walk_kernel<<<dim3(NBATCH), 64, 0, stream>>>(boxesP, mask, rowany, (float4*)d_out);
    } else {
        size_t nms_lds = (size_t)5 * KTOP * 4 + NW32 * 4 + 16;
        nms_fallback_kernel<<<dim3(NBATCH), 1024, nms_lds, stream>>>(boxesP, (float*)d_out);
    }
}

// Round 4
// 518.301 us; speedup vs baseline: 4.2188x; 1.5770x over previous
//
#include <hip/hip_runtime.h>
#include <stdint.h>

#define NBATCH 8
#define NA 262144
#define KTOP 6000
#define PROP 1000
#define NCAND 8192
#define NBINS 4096
#define NMS_THR 0.7f
#define NPAD 6016          // KTOP padded to 94*64
#define MCH 94             // u64 col-chunks per row
#define NW32 188           // ceil(6000/32)
#define LSLOTS 8           // list slots per row

// ---- workspace layout (bytes) ----
static constexpr size_t OFF_HIST    = 0;                          // 8*4096*4 = 131072
static constexpr size_t OFF_CNT     = 131072;                     // 32
static constexpr size_t OFF_ROWCNT  = 131104;                     // 8*6016*4 = 192512
static constexpr size_t ZERO_BYTES  = 323616;                     // hist+cnt+rowcnt
static constexpr size_t OFF_CUT     = 323616;                     // 32
static constexpr size_t OFF_CAND    = 323648;                     // 8*8192*8 = 524288
static constexpr size_t OFF_BOXESP  = 847936;                     // 8*6016*16 = 770048
static constexpr size_t OFF_ROWLIST = 1617984;                    // 8*6016*8*2 = 770048
static constexpr size_t NEEDED      = OFF_ROWLIST + 770048;       // ~2.39 MB

// ---------------- Pass 1: per-batch 4096-bin linear histogram (float4 loads) ----------------
__global__ __launch_bounds__(256) void hist_kernel(const float4* __restrict__ probs4,
                                                   unsigned int* __restrict__ hist) {
    __shared__ unsigned int h[NBINS];
    const int b = blockIdx.y;
    const int t = threadIdx.x;
    for (int i = t; i < NBINS; i += 256) h[i] = 0;
    __syncthreads();
    const float4* p4 = probs4 + (size_t)b * (NA / 2);
    const int base = blockIdx.x * 4096;              // float4 index (8192 anchors/block)
    for (int k = 0; k < 16; ++k) {
        float4 v = p4[base + k * 256 + t];
        int b0 = (int)(v.y * (float)NBINS);
        int b1 = (int)(v.w * (float)NBINS);
        b0 = b0 < 0 ? 0 : (b0 > NBINS - 1 ? NBINS - 1 : b0);
        b1 = b1 < 0 ? 0 : (b1 > NBINS - 1 ? NBINS - 1 : b1);
        atomicAdd(&h[b0], 1u);
        atomicAdd(&h[b1], 1u);
    }
    __syncthreads();
    unsigned int* gh = hist + (size_t)b * NBINS;
    for (int i = t; i < NBINS; i += 256) {
        unsigned int v = h[i];
        if (v) atomicAdd(&gh[i], v);
    }
}

// ---------------- Pass 2: cutoff bin, wave-parallel suffix scan ----------------
__global__ __launch_bounds__(64) void cutoff_kernel(const unsigned int* __restrict__ hist,
                                                    unsigned int* __restrict__ cut) {
    const int b = blockIdx.x;
    const int l = threadIdx.x;
    const unsigned int* h = hist + (size_t)b * NBINS;
    unsigned int s = 0;
    for (int k = 0; k < 64; ++k) s += h[l * 64 + k];
    unsigned int c = s;
    for (int off = 1; off < 64; off <<= 1) {
        unsigned int v = __shfl_down(c, off);
        if (l + off < 64) c += v;
    }
    unsigned long long ball = __ballot(c >= (unsigned)KTOP);
    int csel = 63 - __builtin_clzll(ball);
    unsigned int cnext = (csel < 63) ? __shfl(c, csel + 1) : 0u;
    unsigned int rem = (unsigned)KTOP - cnext;
    unsigned int c2 = h[csel * 64 + l];
    for (int off = 1; off < 64; off <<= 1) {
        unsigned int v = __shfl_down(c2, off);
        if (l + off < 64) c2 += v;
    }
    unsigned long long ball2 = __ballot(c2 >= rem);
    int bsel = 63 - __builtin_clzll(ball2);
    if (l == 0) cut[b] = (unsigned int)(csel * 64 + bsel);
}

// ---------------- Pass 3: compact candidates, block-aggregated atomics ----------------
__global__ __launch_bounds__(256) void compact_kernel(const float4* __restrict__ probs4,
                                                      const unsigned int* __restrict__ cut,
                                                      unsigned int* __restrict__ cnt,
                                                      unsigned long long* __restrict__ cand) {
    __shared__ unsigned int lcnt, lbase;
    const int b = blockIdx.y;
    const int t = threadIdx.x;
    const unsigned int cutb = cut[b];
    if (t == 0) lcnt = 0;
    __syncthreads();
    const float4* p4 = probs4 + (size_t)b * (NA / 2);
    const int base = blockIdx.x * 2048;              // float4 index (4096 anchors/block)
    unsigned long long loc[16];
    int c = 0;
    for (int k = 0; k < 8; ++k) {
        int e = base + k * 256 + t;
        float4 v = p4[e];
        int b0 = (int)(v.y * (float)NBINS);
        int b1 = (int)(v.w * (float)NBINS);
        b0 = b0 < 0 ? 0 : (b0 > NBINS - 1 ? NBINS - 1 : b0);
        b1 = b1 < 0 ? 0 : (b1 > NBINS - 1 ? NBINS - 1 : b1);
        if ((unsigned)b0 >= cutb) {
            unsigned int a = (unsigned)(2 * e);
            loc[c++] = ((unsigned long long)__float_as_uint(v.y) << 32) | (unsigned int)(~a);
        }
        if ((unsigned)b1 >= cutb) {
            unsigned int a = (unsigned)(2 * e + 1);
            loc[c++] = ((unsigned long long)__float_as_uint(v.w) << 32) | (unsigned int)(~a);
        }
    }
    unsigned int off = c ? atomicAdd(&lcnt, (unsigned)c) : 0u;
    __syncthreads();
    if (t == 0) lbase = lcnt ? atomicAdd(&cnt[b], lcnt) : 0u;
    __syncthreads();
    unsigned int gbase = lbase + off;
    for (int i = 0; i < c; ++i)
        if (gbase + i < NCAND)
            cand[(size_t)b * NCAND + gbase + i] = loc[i];
}

// ---------------- Pass 4: bitonic sort (desc) + gather + box decode ----------------
__global__ __launch_bounds__(1024) void sort_box_kernel(const unsigned long long* __restrict__ cand,
                                                        const unsigned int* __restrict__ cnt,
                                                        const float4* __restrict__ anchors,
                                                        const float4* __restrict__ bbox,
                                                        float4* __restrict__ boxesP) {
    extern __shared__ unsigned long long keys[];  // NCAND
    const int b = blockIdx.x;
    unsigned int n = cnt[b]; if (n > NCAND) n = NCAND;
    const unsigned long long* cb = cand + (size_t)b * NCAND;
    for (int i = threadIdx.x; i < NCAND; i += 1024)
        keys[i] = (i < (int)n) ? cb[i] : 0ull;     // 0 sorts last (desc)
    __syncthreads();
    for (int k = 2; k <= NCAND; k <<= 1) {
        for (int j = k >> 1; j > 0; j >>= 1) {
            for (int i = threadIdx.x; i < NCAND; i += 1024) {
                int ixj = i ^ j;
                if (ixj > i) {
                    unsigned long long a0 = keys[i], a1 = keys[ixj];
                    bool desc = (i & k) == 0;
                    if (desc ? (a0 < a1) : (a0 > a1)) { keys[i] = a1; keys[ixj] = a0; }
                }
            }
            __syncthreads();
        }
    }
    for (int r = threadIdx.x; r < KTOP; r += 1024) {
        unsigned long long e = keys[r];
        unsigned int idx = ~(unsigned int)(e & 0xFFFFFFFFull);
        float4 anc = anchors[(size_t)b * NA + idx];
        float4 del = bbox[(size_t)b * NA + idx];
        float dy = del.x * 0.1f, dx = del.y * 0.1f, dh = del.z * 0.2f, dw = del.w * 0.2f;
        float h = anc.z - anc.x, w = anc.w - anc.y;
        float cy = anc.x + 0.5f * h + dy * h;
        float cx = anc.y + 0.5f * w + dx * w;
        h = h * expf(dh);
        w = w * expf(dw);
        float y1v = fminf(fmaxf(cy - 0.5f * h, 0.f), 1.f);
        float x1v = fminf(fmaxf(cx - 0.5f * w, 0.f), 1.f);
        float y2v = fminf(fmaxf(cy + 0.5f * h, 0.f), 1.f);
        float x2v = fminf(fmaxf(cx + 0.5f * w, 0.f), 1.f);
        boxesP[(size_t)b * NPAD + r] = make_float4(y1v, x1v, y2v, x2v);
    }
    for (int r = KTOP + threadIdx.x; r < NPAD; r += 1024)
        boxesP[(size_t)b * NPAD + r] = make_float4(0.f, 0.f, 0.f, 0.f);
}

// ---------------- Pass 5a: IoU suppression sparse lists ----------------
// For each row i, append column indices j>i with IoU>thr (up to LSLOTS; count is exact).
__global__ __launch_bounds__(256) void iou_kernel(const float4* __restrict__ boxesP,
                                                  unsigned int* __restrict__ rowcnt,
                                                  unsigned short* __restrict__ rowlist) {
    const int bx = blockIdx.x;          // group of 4 col chunks
    const int cy = blockIdx.y;          // row chunk
    const int b  = blockIdx.z;
    if (bx * 4 + 3 < cy) return;        // whole block below diagonal
    const int t  = threadIdx.x;
    __shared__ float4 cbx[256];
    __shared__ float  car[256];
    int cj = bx * 256 + t;
    float4 c4 = (cj < NPAD) ? boxesP[(size_t)b * NPAD + cj] : make_float4(0.f,0.f,0.f,0.f);
    cbx[t] = c4;
    car[t] = (c4.z - c4.x) * (c4.w - c4.y);
    __syncthreads();
    const int cx = bx * 4 + (t >> 6);
    const int tl = t & 63;
    if (cx >= MCH || cx < cy) return;
    const int i = cy * 64 + tl;
    float4 r4 = boxesP[(size_t)b * NPAD + i];
    float rar = (r4.z - r4.x) * (r4.w - r4.y);
    const int cb0 = (t >> 6) * 64;
    unsigned long long m = 0ull;
    #pragma unroll 8
    for (int j = 0; j < 64; ++j) {
        float4 q = cbx[cb0 + j];
        float yy1 = fmaxf(r4.x, q.x), xx1 = fmaxf(r4.y, q.y);
        float yy2 = fminf(r4.z, q.z), xx2 = fminf(r4.w, q.w);
        float inter = fmaxf(yy2 - yy1, 0.f) * fmaxf(xx2 - xx1, 0.f);
        float uni = rar + car[cb0 + j] - inter;
        float iou = inter / fmaxf(uni, 1e-12f);
        m |= ((unsigned long long)(iou > NMS_THR)) << j;
    }
    unsigned long long allow = (cx > cy) ? ~0ull : ((tl == 63) ? 0ull : (~0ull << (tl + 1)));
    m &= allow;
    while (m) {
        int j = __builtin_ctzll(m); m &= m - 1ull;
        int jg = cx * 64 + j;
        unsigned int pos = atomicAdd(&rowcnt[(size_t)b * NPAD + i], 1u);
        if (pos < LSLOTS)
            rowlist[((size_t)b * NPAD + i) * LSLOTS + pos] = (unsigned short)jg;
    }
}

// ---------------- Pass 5b: serial walk, 1 wave per batch, LDS-resident lists ----------------
__global__ __launch_bounds__(64) void walk_kernel(const float4* __restrict__ boxesP,
                                                  const unsigned int* __restrict__ rowcnt,
                                                  const unsigned short* __restrict__ rowlist,
                                                  float4* __restrict__ out) {
    extern __shared__ char smraw[];
    uint4*         rlS     = (uint4*)smraw;                          // [NPAD] 16B rows = 96256
    unsigned int*  removed = (unsigned int*)(smraw + 96256);         // 188 u32
    unsigned int*  hasup   = removed + NW32 + 1;                     // 188 u32 (bit per row)
    unsigned int*  outIdx  = hasup + NW32 + 1;                       // PROP u32
    unsigned char* rcnt    = (unsigned char*)(outIdx + PROP);        // NPAD u8
    volatile unsigned int* vrem = removed;

    const int b = blockIdx.x;
    const int t = threadIdx.x;

    for (int i = t; i < NW32; i += 64) {
        removed[i] = (i == NW32 - 1) ? 0xFFFF0000u : 0u;
        hasup[i] = 0u;
    }
    __syncthreads();
    const unsigned int* rc = rowcnt + (size_t)b * NPAD;
    for (int i = t; i < NPAD; i += 64) {
        unsigned int c = rc[i];
        rcnt[i] = (unsigned char)(c > 255u ? 255u : c);
        if (c) atomicOr(&hasup[i >> 5], 1u << (i & 31));
    }
    const uint4* rl = (const uint4*)(rowlist + (size_t)b * NPAD * LSLOTS);
    for (int i = t; i < NPAD; i += 64) rlS[i] = rl[i];
    __syncthreads();

    // serial walk — all lanes execute identically; LDS writes by t==0 / atomics
    int w = 0;
    unsigned int curRem = removed[0];
    unsigned int curHas = hasup[0];
    int sel = 0;
    while (sel < PROP) {
        unsigned int avail = ~curRem;
        if (!avail) {
            if (++w >= NW32) break;
            curRem = vrem[w];
            curHas = hasup[w];
            continue;
        }
        int bit = __ffs(avail) - 1;
        int i = (w << 5) + bit;
        curRem |= 1u << bit;
        if (t == 0) outIdx[sel] = (unsigned int)i;
        ++sel;
        if ((curHas >> bit) & 1u) {
            int c = rcnt[i];
            if (c <= LSLOTS) {
                uint4 row = rlS[i];
                #pragma unroll
                for (int k = 0; k < LSLOTS; ++k) {
                    if (k >= c) break;
                    unsigned int word32 = (k < 2) ? row.x : (k < 4) ? row.y : (k < 6) ? row.z : row.w;
                    unsigned int jg = (k & 1) ? (word32 >> 16) : (word32 & 0xFFFFu);
                    int wj = (int)(jg >> 5);
                    unsigned int mb = 1u << (jg & 31u);
                    if (wj == w) curRem |= mb;
                    else if (t == 0) atomicOr(&removed[wj], mb);
                }
            } else {
                // overflow: recompute row i vs all j>i (rare/never for this input)
                float4 bi = boxesP[(size_t)b * NPAD + i];
                float ar_i = (bi.z - bi.x) * (bi.w - bi.y);
                for (int j0 = 0; j0 < NPAD; j0 += 64) {
                    int j = j0 + t;
                    bool sup = false;
                    if (j > i) {
                        float4 q = boxesP[(size_t)b * NPAD + j];
                        float yy1 = fmaxf(bi.x, q.x), xx1 = fmaxf(bi.y, q.y);
                        float yy2 = fminf(bi.z, q.z), xx2 = fminf(bi.w, q.w);
                        float inter = fmaxf(yy2 - yy1, 0.f) * fmaxf(xx2 - xx1, 0.f);
                        float uni = ar_i + (q.z - q.x) * (q.w - q.y) - inter;
                        sup = (inter / fmaxf(uni, 1e-12f)) > NMS_THR;
                    }
                    if (sup) atomicOr(&removed[j >> 5], 1u << (j & 31));
                }
                __syncthreads();
                curRem |= vrem[w];
            }
        }
    }
    __syncthreads();
    float4* ob = out + (size_t)b * PROP;
    for (int k = t; k < PROP; k += 64) {
        float4 v = (k < sel) ? boxesP[(size_t)b * NPAD + outIdx[k]]
                             : make_float4(0.f, 0.f, 0.f, 0.f);
        ob[k] = v;
    }
}

extern "C" void kernel_launch(void* const* d_in, const int* in_sizes, int n_in,
                              void* d_out, int out_size, void* d_ws, size_t ws_size,
                              hipStream_t stream) {
    const float4* probs4  = (const float4*)d_in[0];
    const float4* bbox    = (const float4*)d_in[1];
    const float4* anchors = (const float4*)d_in[2];
    char* ws = (char*)d_ws;
    unsigned int* hist         = (unsigned int*)(ws + OFF_HIST);
    unsigned int* cnt          = (unsigned int*)(ws + OFF_CNT);
    unsigned int* rowcnt       = (unsigned int*)(ws + OFF_ROWCNT);
    unsigned int* cut          = (unsigned int*)(ws + OFF_CUT);
    unsigned long long* cand   = (unsigned long long*)(ws + OFF_CAND);
    float4* boxesP             = (float4*)(ws + OFF_BOXESP);
    unsigned short* rowlist    = (unsigned short*)(ws + OFF_ROWLIST);

    hipMemsetAsync(d_ws, 0, ZERO_BYTES, stream);   // hist + cnt + rowcnt

    hist_kernel<<<dim3(NA / 8192, NBATCH), 256, 0, stream>>>(probs4, hist);
    cutoff_kernel<<<dim3(NBATCH), 64, 0, stream>>>(hist, cut);
    compact_kernel<<<dim3(NA / 4096, NBATCH), 256, 0, stream>>>(probs4, cut, cnt, cand);
    sort_box_kernel<<<dim3(NBATCH), 1024, NCAND * 8, stream>>>(cand, cnt, anchors, bbox, boxesP);
    iou_kernel<<<dim3((MCH + 3) / 4, MCH, NBATCH), 256, 0, stream>>>(boxesP, rowcnt, rowlist);
    size_t walk_lds = 96256 + (NW32 + 1) * 4 * 2 + PROP * 4 + NPAD + 64;  // ~107.9 KB
    walk_kernel<<<dim3(NBATCH), 64, walk_lds, stream>>>(boxesP, rowcnt, rowlist, (float4*)d_out);
}

// Round 5
// 447.865 us; speedup vs baseline: 4.8823x; 1.1573x over previous
//
#include <hip/hip_runtime.h>
#include <stdint.h>

#define NBATCH 8
#define NA 262144
#define KTOP 6000
#define PROP 1000
#define NCAND 8192
#define NBINS 4096
#define NMS_THR 0.7f
#define NPAD 6016          // KTOP padded to 94*64
#define MCH 94             // col-chunks per row
#define NW32 188           // ceil(6000/32)
#define LSLOTS 7           // u16 list slots per row (slot 0 = count)

// ---- workspace layout (bytes) ----
static constexpr size_t OFF_HIST    = 0;                          // 8*4096*4 = 131072
static constexpr size_t OFF_CNT     = 131072;                     // 32
static constexpr size_t OFF_ROWCNT  = 131104;                     // 8*6016*4 = 192512
static constexpr size_t ZERO_BYTES  = 323616;                     // hist+cnt+rowcnt
static constexpr size_t OFF_CUT     = 323616;                     // 32
static constexpr size_t OFF_CAND    = 323648;                     // 8*8192*8 = 524288
static constexpr size_t OFF_BOXESP  = 847936;                     // 8*6016*16 = 770048
static constexpr size_t OFF_ROWLIST = 1617984;                    // 8*6016*8*2 = 770048

// ---------------- Pass 1: per-batch 4096-bin linear histogram (float4 loads) ----------------
__global__ __launch_bounds__(256) void hist_kernel(const float4* __restrict__ probs4,
                                                   unsigned int* __restrict__ hist) {
    __shared__ unsigned int h[NBINS];
    const int b = blockIdx.y;
    const int t = threadIdx.x;
    for (int i = t; i < NBINS; i += 256) h[i] = 0;
    __syncthreads();
    const float4* p4 = probs4 + (size_t)b * (NA / 2);
    const int base = blockIdx.x * 4096;              // float4 index (8192 anchors/block)
    for (int k = 0; k < 16; ++k) {
        float4 v = p4[base + k * 256 + t];
        int b0 = (int)(v.y * (float)NBINS);
        int b1 = (int)(v.w * (float)NBINS);
        b0 = b0 < 0 ? 0 : (b0 > NBINS - 1 ? NBINS - 1 : b0);
        b1 = b1 < 0 ? 0 : (b1 > NBINS - 1 ? NBINS - 1 : b1);
        atomicAdd(&h[b0], 1u);
        atomicAdd(&h[b1], 1u);
    }
    __syncthreads();
    unsigned int* gh = hist + (size_t)b * NBINS;
    for (int i = t; i < NBINS; i += 256) {
        unsigned int v = h[i];
        if (v) atomicAdd(&gh[i], v);
    }
}

// ---------------- Pass 2: cutoff bin, wave-parallel suffix scan ----------------
__global__ __launch_bounds__(64) void cutoff_kernel(const unsigned int* __restrict__ hist,
                                                    unsigned int* __restrict__ cut) {
    const int b = blockIdx.x;
    const int l = threadIdx.x;
    const unsigned int* h = hist + (size_t)b * NBINS;
    unsigned int s = 0;
    for (int k = 0; k < 64; ++k) s += h[l * 64 + k];
    unsigned int c = s;
    for (int off = 1; off < 64; off <<= 1) {
        unsigned int v = __shfl_down(c, off);
        if (l + off < 64) c += v;
    }
    unsigned long long ball = __ballot(c >= (unsigned)KTOP);
    int csel = 63 - __builtin_clzll(ball);
    unsigned int cnext = (csel < 63) ? __shfl(c, csel + 1) : 0u;
    unsigned int rem = (unsigned)KTOP - cnext;
    unsigned int c2 = h[csel * 64 + l];
    for (int off = 1; off < 64; off <<= 1) {
        unsigned int v = __shfl_down(c2, off);
        if (l + off < 64) c2 += v;
    }
    unsigned long long ball2 = __ballot(c2 >= rem);
    int bsel = 63 - __builtin_clzll(ball2);
    if (l == 0) cut[b] = (unsigned int)(csel * 64 + bsel);
}

// ---------------- Pass 3: compact candidates, block-aggregated atomics ----------------
__global__ __launch_bounds__(256) void compact_kernel(const float4* __restrict__ probs4,
                                                      const unsigned int* __restrict__ cut,
                                                      unsigned int* __restrict__ cnt,
                                                      unsigned long long* __restrict__ cand) {
    __shared__ unsigned int lcnt, lbase;
    const int b = blockIdx.y;
    const int t = threadIdx.x;
    const unsigned int cutb = cut[b];
    if (t == 0) lcnt = 0;
    __syncthreads();
    const float4* p4 = probs4 + (size_t)b * (NA / 2);
    const int base = blockIdx.x * 2048;              // float4 index (4096 anchors/block)
    unsigned long long loc[16];
    int c = 0;
    for (int k = 0; k < 8; ++k) {
        int e = base + k * 256 + t;
        float4 v = p4[e];
        int b0 = (int)(v.y * (float)NBINS);
        int b1 = (int)(v.w * (float)NBINS);
        b0 = b0 < 0 ? 0 : (b0 > NBINS - 1 ? NBINS - 1 : b0);
        b1 = b1 < 0 ? 0 : (b1 > NBINS - 1 ? NBINS - 1 : b1);
        if ((unsigned)b0 >= cutb) {
            unsigned int a = (unsigned)(2 * e);
            loc[c++] = ((unsigned long long)__float_as_uint(v.y) << 32) | (unsigned int)(~a);
        }
        if ((unsigned)b1 >= cutb) {
            unsigned int a = (unsigned)(2 * e + 1);
            loc[c++] = ((unsigned long long)__float_as_uint(v.w) << 32) | (unsigned int)(~a);
        }
    }
    unsigned int off = c ? atomicAdd(&lcnt, (unsigned)c) : 0u;
    __syncthreads();
    if (t == 0) lbase = lcnt ? atomicAdd(&cnt[b], lcnt) : 0u;
    __syncthreads();
    unsigned int gbase = lbase + off;
    for (int i = 0; i < c; ++i)
        if (gbase + i < NCAND)
            cand[(size_t)b * NCAND + gbase + i] = loc[i];
}

// ---------------- Pass 4: hybrid register/shfl/LDS bitonic sort + box decode ----------------
__device__ __forceinline__ unsigned long long shfl_xor_u64(unsigned long long v, int m) {
    int lo = __shfl_xor((int)(unsigned)(v & 0xFFFFFFFFull), m);
    int hi = __shfl_xor((int)(unsigned)(v >> 32), m);
    return ((unsigned long long)(unsigned)hi << 32) | (unsigned)lo;
}
#define SWZ(i_) ((i_) ^ (((i_) >> 3) & 7))

template<int J>
__device__ __forceinline__ void regPass(unsigned long long (&r)[8], int base, unsigned k) {
    #pragma unroll
    for (int e = 0; e < 8; ++e) {
        if ((e & J) == 0) {
            const int p = e | J;
            bool dir = (((unsigned)(base + e) & k) == 0);   // desc block
            unsigned long long lo = r[e], hi = r[p];
            bool sw = dir ? (lo < hi) : (lo > hi);
            r[e] = sw ? hi : lo;
            r[p] = sw ? lo : hi;
        }
    }
}

__device__ __forceinline__ void shflPass(unsigned long long (&r)[8], int base, int lane,
                                         unsigned k, unsigned j) {
    const int jj = (int)(j >> 3);
    const bool isHi = (lane & jj) != 0;
    #pragma unroll
    for (int e = 0; e < 8; ++e) {
        unsigned long long other = shfl_xor_u64(r[e], jj);
        bool dir = (((unsigned)(base + e) & k) == 0);
        bool takeMax = dir != isHi;
        bool gt = r[e] > other;
        r[e] = (takeMax == gt) ? r[e] : other;
    }
}

__global__ __launch_bounds__(1024) void sort_box_kernel(const unsigned long long* __restrict__ cand,
                                                        const unsigned int* __restrict__ cnt,
                                                        const float4* __restrict__ anchors,
                                                        const float4* __restrict__ bbox,
                                                        float4* __restrict__ boxesP) {
    extern __shared__ unsigned long long keys[];  // NCAND (swizzled)
    const int b = blockIdx.x;
    const int t = threadIdx.x;
    const int lane = t & 63;
    const int base = t * 8;
    unsigned int n = cnt[b]; if (n > NCAND) n = NCAND;
    const unsigned long long* cb = cand + (size_t)b * NCAND;

    unsigned long long r[8];
    #pragma unroll
    for (int e = 0; e < 8; ++e)
        r[e] = ((unsigned)(base + e) < n) ? cb[base + e] : 0ull;   // 0 sorts last (desc)

    // k = 2..512 entirely in registers + wave shuffles (no barriers)
    for (unsigned k = 2; k <= 512; k <<= 1) {
        for (unsigned j = k >> 1; j >= 8; j >>= 1) shflPass(r, base, lane, k, j);
        if (k >= 8) regPass<4>(r, base, k);
        if (k >= 4) regPass<2>(r, base, k);
        regPass<1>(r, base, k);
    }
    #pragma unroll
    for (int e = 0; e < 8; ++e) keys[SWZ(base + e)] = r[e];
    __syncthreads();

    // k = 1024..8192: LDS passes for j>=512, then shfl/reg batch
    for (unsigned k = 1024; k <= NCAND; k <<= 1) {
        for (unsigned j = k >> 1; j >= 512; j >>= 1) {
            for (int i = t; i < NCAND; i += 1024) {
                int ixj = i ^ (int)j;
                if (ixj > i) {
                    unsigned long long a0 = keys[SWZ(i)], a1 = keys[SWZ(ixj)];
                    bool dir = (((unsigned)i & k) == 0);
                    if (dir ? (a0 < a1) : (a0 > a1)) { keys[SWZ(i)] = a1; keys[SWZ(ixj)] = a0; }
                }
            }
            __syncthreads();
        }
        #pragma unroll
        for (int e = 0; e < 8; ++e) r[e] = keys[SWZ(base + e)];
        for (unsigned j = 256; j >= 8; j >>= 1) shflPass(r, base, lane, k, j);
        regPass<4>(r, base, k);
        regPass<2>(r, base, k);
        regPass<1>(r, base, k);
        #pragma unroll
        for (int e = 0; e < 8; ++e) keys[SWZ(base + e)] = r[e];
        __syncthreads();
    }

    for (int rI = t; rI < KTOP; rI += 1024) {
        unsigned long long e = keys[SWZ(rI)];
        unsigned int idx = ~(unsigned int)(e & 0xFFFFFFFFull);
        float4 anc = anchors[(size_t)b * NA + idx];
        float4 del = bbox[(size_t)b * NA + idx];
        float dy = del.x * 0.1f, dx = del.y * 0.1f, dh = del.z * 0.2f, dw = del.w * 0.2f;
        float h = anc.z - anc.x, w = anc.w - anc.y;
        float cy = anc.x + 0.5f * h + dy * h;
        float cx = anc.y + 0.5f * w + dx * w;
        h = h * expf(dh);
        w = w * expf(dw);
        float y1v = fminf(fmaxf(cy - 0.5f * h, 0.f), 1.f);
        float x1v = fminf(fmaxf(cx - 0.5f * w, 0.f), 1.f);
        float y2v = fminf(fmaxf(cy + 0.5f * h, 0.f), 1.f);
        float x2v = fminf(fmaxf(cx + 0.5f * w, 0.f), 1.f);
        boxesP[(size_t)b * NPAD + rI] = make_float4(y1v, x1v, y2v, x2v);
    }
    for (int rI = KTOP + t; rI < NPAD; rI += 1024)
        boxesP[(size_t)b * NPAD + rI] = make_float4(0.f, 0.f, 0.f, 0.f);
}

// ---------------- Pass 5a: IoU suppression sparse lists ----------------
// Row layout (8 x u16): [0]=unused-in-global (count filled at walk load), [1..7]=suppressed idx.
__global__ __launch_bounds__(256) void iou_kernel(const float4* __restrict__ boxesP,
                                                  unsigned int* __restrict__ rowcnt,
                                                  unsigned short* __restrict__ rowlist) {
    const int bx = blockIdx.x;          // group of 4 col chunks
    const int cy = blockIdx.y;          // row chunk
    const int b  = blockIdx.z;
    if (bx * 4 + 3 < cy) return;
    const int t  = threadIdx.x;
    __shared__ float4 cbx[256];
    __shared__ float  car[256];
    int cj = bx * 256 + t;
    float4 c4 = (cj < NPAD) ? boxesP[(size_t)b * NPAD + cj] : make_float4(0.f,0.f,0.f,0.f);
    cbx[t] = c4;
    car[t] = (c4.z - c4.x) * (c4.w - c4.y);
    __syncthreads();
    const int cx = bx * 4 + (t >> 6);
    const int tl = t & 63;
    if (cx >= MCH || cx < cy) return;
    const int i = cy * 64 + tl;
    float4 r4 = boxesP[(size_t)b * NPAD + i];
    float rar = (r4.z - r4.x) * (r4.w - r4.y);
    const int cb0 = (t >> 6) * 64;
    unsigned long long m = 0ull;
    #pragma unroll 8
    for (int j = 0; j < 64; ++j) {
        float4 q = cbx[cb0 + j];
        float yy1 = fmaxf(r4.x, q.x), xx1 = fmaxf(r4.y, q.y);
        float yy2 = fminf(r4.z, q.z), xx2 = fminf(r4.w, q.w);
        float inter = fmaxf(yy2 - yy1, 0.f) * fmaxf(xx2 - xx1, 0.f);
        float uni = rar + car[cb0 + j] - inter;
        float iou = inter / fmaxf(uni, 1e-12f);
        m |= ((unsigned long long)(iou > NMS_THR)) << j;
    }
    unsigned long long allow = (cx > cy) ? ~0ull : ((tl == 63) ? 0ull : (~0ull << (tl + 1)));
    m &= allow;
    while (m) {
        int j = __builtin_ctzll(m); m &= m - 1ull;
        int jg = cx * 64 + j;
        unsigned int pos = atomicAdd(&rowcnt[(size_t)b * NPAD + i], 1u);
        if (pos < LSLOTS)
            rowlist[((size_t)b * NPAD + i) * 8 + 1 + pos] = (unsigned short)jg;
    }
}

// ---------------- Pass 5b: serial walk, register-distributed bitmask, wave 0 ----------------
#define GETWORD(w_) do { int rg_ = (w_) >> 6; \
    unsigned rr_ = rg_ == 0 ? rem0 : (rg_ == 1 ? rem1 : rem2); \
    unsigned hh_ = rg_ == 0 ? has0 : (rg_ == 1 ? has1 : has2); \
    curRem = __shfl(rr_, (w_) & 63); curHas = __shfl(hh_, (w_) & 63); } while (0)

#define OWNOR(wj_, mb_) do { int rg_ = (wj_) >> 6; \
    unsigned mm_ = (lane == ((wj_) & 63)) ? (mb_) : 0u; \
    if (rg_ == 0) rem0 |= mm_; else if (rg_ == 1) rem1 |= mm_; else rem2 |= mm_; } while (0)

__global__ __launch_bounds__(256) void walk_kernel(const float4* __restrict__ boxesP,
                                                   const unsigned int* __restrict__ rowcnt,
                                                   const uint4* __restrict__ rowlist4,
                                                   float4* __restrict__ out) {
    extern __shared__ char smraw[];
    uint4*        rlS    = (uint4*)smraw;                            // [NPAD] = 96256 B
    unsigned int* hasupS = (unsigned int*)(smraw + 96256);           // 192 u32
    unsigned int* outIdx = hasupS + 192;                             // PROP u32
    int*          selS   = (int*)(outIdx + PROP);

    const int b = blockIdx.x;
    const int t = threadIdx.x;

    if (t < 192) hasupS[t] = 0;
    __syncthreads();
    const unsigned int* rc = rowcnt + (size_t)b * NPAD;
    const uint4* rl = rowlist4 + (size_t)b * NPAD;
    for (int i = t; i < NPAD; i += 256) {
        unsigned int c = rc[i];
        uint4 v = rl[i];
        v.x = (v.x & 0xFFFF0000u) | (c > 0xFFFFu ? 0xFFFFu : c);     // count in slot 0
        rlS[i] = v;
        if (c) atomicOr(&hasupS[i >> 5], 1u << (i & 31));
    }
    __syncthreads();

    if (t < 64) {
        const int lane = t;
        // lane l owns words l, 64+l, 128+l of the removed/has bitmasks
        unsigned int rem0 = 0u, rem1 = 0u;
        unsigned int rem2 = (128 + lane > 187) ? 0xFFFFFFFFu
                          : (128 + lane == 187) ? 0xFFFF0000u : 0u;  // rows >= 6000 invalid
        unsigned int has0 = hasupS[lane];
        unsigned int has1 = hasupS[64 + lane];
        unsigned int has2 = (128 + lane < NW32) ? hasupS[128 + lane] : 0u;

        int w = 0, sel = 0;
        unsigned int curRem, curHas;
        GETWORD(0);
        while (sel < PROP) {
            unsigned int avail = ~curRem;
            if (!avail) {
                if (++w >= NW32) break;
                GETWORD(w);
                continue;
            }
            int bit = __ffs(avail) - 1;
            int i = (w << 5) + bit;
            unsigned int selm = 1u << bit;
            curRem |= selm;
            OWNOR(w, selm);
            if (lane == 0) outIdx[sel] = (unsigned int)i;
            ++sel;
            if ((curHas >> bit) & 1u) {
                uint4 row = rlS[i];                                  // broadcast LDS read
                unsigned int c = row.x & 0xFFFFu;
                if (c <= (unsigned)LSLOTS) {
                    unsigned int s16[7] = { row.x >> 16, row.y & 0xFFFFu, row.y >> 16,
                                            row.z & 0xFFFFu, row.z >> 16,
                                            row.w & 0xFFFFu, row.w >> 16 };
                    #pragma unroll
                    for (int kk = 0; kk < LSLOTS; ++kk) {
                        if (kk >= (int)c) break;
                        unsigned int jg = s16[kk];
                        int wj = (int)(jg >> 5);
                        unsigned int mb = 1u << (jg & 31u);
                        OWNOR(wj, mb);
                        if (wj == w) curRem |= mb;
                    }
                } else {
                    // overflow (rare): recompute row i vs all j>i with 64 lanes
                    float4 bi = boxesP[(size_t)b * NPAD + i];
                    float ari = (bi.z - bi.x) * (bi.w - bi.y);
                    for (int j0 = 0; j0 < NPAD; j0 += 64) {
                        int j = j0 + lane;
                        bool sup = false;
                        if (j > i) {
                            float4 q = boxesP[(size_t)b * NPAD + j];
                            float yy1 = fmaxf(bi.x, q.x), xx1 = fmaxf(bi.y, q.y);
                            float yy2 = fminf(bi.z, q.z), xx2 = fminf(bi.w, q.w);
                            float inter = fmaxf(yy2 - yy1, 0.f) * fmaxf(xx2 - xx1, 0.f);
                            float uni = ari + (q.z - q.x) * (q.w - q.y) - inter;
                            sup = (inter / fmaxf(uni, 1e-12f)) > NMS_THR;
                        }
                        unsigned long long bal = __ballot(sup);
                        int wA = j0 >> 5;
                        OWNOR(wA, (unsigned int)bal);
                        OWNOR(wA + 1, (unsigned int)(bal >> 32));
                    }
                    GETWORD(w);   // refresh current word after bulk update
                }
            }
        }
        if (lane == 0) *selS = sel;
    }
    __syncthreads();
    int sel = *selS;
    float4* ob = out + (size_t)b * PROP;
    for (int k = t; k < PROP; k += 256) {
        float4 v = (k < sel) ? boxesP[(size_t)b * NPAD + outIdx[k]]
                             : make_float4(0.f, 0.f, 0.f, 0.f);
        ob[k] = v;
    }
}

extern "C" void kernel_launch(void* const* d_in, const int* in_sizes, int n_in,
                              void* d_out, int out_size, void* d_ws, size_t ws_size,
                              hipStream_t stream) {
    const float4* probs4  = (const float4*)d_in[0];
    const float4* bbox    = (const float4*)d_in[1];
    const float4* anchors = (const float4*)d_in[2];
    char* ws = (char*)d_ws;
    unsigned int* hist       = (unsigned int*)(ws + OFF_HIST);
    unsigned int* cnt        = (unsigned int*)(ws + OFF_CNT);
    unsigned int* rowcnt     = (unsigned int*)(ws + OFF_ROWCNT);
    unsigned int* cut        = (unsigned int*)(ws + OFF_CUT);
    unsigned long long* cand = (unsigned long long*)(ws + OFF_CAND);
    float4* boxesP           = (float4*)(ws + OFF_BOXESP);
    unsigned short* rowlist  = (unsigned short*)(ws + OFF_ROWLIST);

    hipMemsetAsync(d_ws, 0, ZERO_BYTES, stream);   // hist + cnt + rowcnt

    hist_kernel<<<dim3(NA / 8192, NBATCH), 256, 0, stream>>>(probs4, hist);
    cutoff_kernel<<<dim3(NBATCH), 64, 0, stream>>>(hist, cut);
    compact_kernel<<<dim3(NA / 4096, NBATCH), 256, 0, stream>>>(probs4, cut, cnt, cand);
    sort_box_kernel<<<dim3(NBATCH), 1024, NCAND * 8, stream>>>(cand, cnt, anchors, bbox, boxesP);
    iou_kernel<<<dim3((MCH + 3) / 4, MCH, NBATCH), 256, 0, stream>>>(boxesP, rowcnt, rowlist);
    size_t walk_lds = 96256 + 192 * 4 + PROP * 4 + 16;   // ~101 KB
    walk_kernel<<<dim3(NBATCH), 256, walk_lds, stream>>>(boxesP, rowcnt, (const uint4*)rowlist,
                                                         (float4*)d_out);
}

// Round 6
// 291.893 us; speedup vs baseline: 7.4912x; 1.5343x over previous
//
#include <hip/hip_runtime.h>
#include <stdint.h>

#define NBATCH 8
#define NA 262144
#define KTOP 6000
#define PROP 1000
#define NCAND 8192
#define NBINS 4096
#define NMS_THR 0.7f
#define NPAD 6016          // KTOP padded to 94*64
#define MCH 94             // col-chunks per row
#define NW32 188           // ceil(6000/32)
#define LSLOTS 7           // u16 list slots per row (slot 0 = count)

// ---- workspace layout (bytes) ----
static constexpr size_t OFF_HIST    = 0;                          // 8*4096*4 = 131072
static constexpr size_t OFF_CNT     = 131072;                     // 32
static constexpr size_t OFF_ROWCNT  = 131104;                     // 8*6016*4 = 192512
static constexpr size_t ZERO_BYTES  = 323616;                     // hist+cnt+rowcnt
static constexpr size_t OFF_CUT     = 323616;                     // 32
static constexpr size_t OFF_CAND    = 323648;                     // 8*8192*8 = 524288
static constexpr size_t OFF_BOXESP  = 847936;                     // 8*6016*16 = 770048
static constexpr size_t OFF_ROWLIST = 1617984;                    // 8*6016*8*2 = 770048

// ---------------- Pass 1: per-batch 4096-bin linear histogram (float4 loads) ----------------
__global__ __launch_bounds__(256) void hist_kernel(const float4* __restrict__ probs4,
                                                   unsigned int* __restrict__ hist) {
    __shared__ unsigned int h[NBINS];
    const int b = blockIdx.y;
    const int t = threadIdx.x;
    for (int i = t; i < NBINS; i += 256) h[i] = 0;
    __syncthreads();
    const float4* p4 = probs4 + (size_t)b * (NA / 2);
    const int base = blockIdx.x * 4096;              // float4 index (8192 anchors/block)
    for (int k = 0; k < 16; ++k) {
        float4 v = p4[base + k * 256 + t];
        int b0 = (int)(v.y * (float)NBINS);
        int b1 = (int)(v.w * (float)NBINS);
        b0 = b0 < 0 ? 0 : (b0 > NBINS - 1 ? NBINS - 1 : b0);
        b1 = b1 < 0 ? 0 : (b1 > NBINS - 1 ? NBINS - 1 : b1);
        atomicAdd(&h[b0], 1u);
        atomicAdd(&h[b1], 1u);
    }
    __syncthreads();
    unsigned int* gh = hist + (size_t)b * NBINS;
    for (int i = t; i < NBINS; i += 256) {
        unsigned int v = h[i];
        if (v) atomicAdd(&gh[i], v);
    }
}

// ---------------- Pass 2: cutoff bin, wave-parallel suffix scan ----------------
__global__ __launch_bounds__(64) void cutoff_kernel(const unsigned int* __restrict__ hist,
                                                    unsigned int* __restrict__ cut) {
    const int b = blockIdx.x;
    const int l = threadIdx.x;
    const unsigned int* h = hist + (size_t)b * NBINS;
    unsigned int s = 0;
    for (int k = 0; k < 64; ++k) s += h[l * 64 + k];
    unsigned int c = s;
    for (int off = 1; off < 64; off <<= 1) {
        unsigned int v = __shfl_down(c, off);
        if (l + off < 64) c += v;
    }
    unsigned long long ball = __ballot(c >= (unsigned)KTOP);
    int csel = 63 - __builtin_clzll(ball);
    unsigned int cnext = (csel < 63) ? __shfl(c, csel + 1) : 0u;
    unsigned int rem = (unsigned)KTOP - cnext;
    unsigned int c2 = h[csel * 64 + l];
    for (int off = 1; off < 64; off <<= 1) {
        unsigned int v = __shfl_down(c2, off);
        if (l + off < 64) c2 += v;
    }
    unsigned long long ball2 = __ballot(c2 >= rem);
    int bsel = 63 - __builtin_clzll(ball2);
    if (l == 0) cut[b] = (unsigned int)(csel * 64 + bsel);
}

// ---------------- Pass 3: compact candidates, block-aggregated atomics ----------------
__global__ __launch_bounds__(256) void compact_kernel(const float4* __restrict__ probs4,
                                                      const unsigned int* __restrict__ cut,
                                                      unsigned int* __restrict__ cnt,
                                                      unsigned long long* __restrict__ cand) {
    __shared__ unsigned int lcnt, lbase;
    const int b = blockIdx.y;
    const int t = threadIdx.x;
    const unsigned int cutb = cut[b];
    if (t == 0) lcnt = 0;
    __syncthreads();
    const float4* p4 = probs4 + (size_t)b * (NA / 2);
    const int base = blockIdx.x * 2048;              // float4 index (4096 anchors/block)
    unsigned long long loc[16];
    int c = 0;
    for (int k = 0; k < 8; ++k) {
        int e = base + k * 256 + t;
        float4 v = p4[e];
        int b0 = (int)(v.y * (float)NBINS);
        int b1 = (int)(v.w * (float)NBINS);
        b0 = b0 < 0 ? 0 : (b0 > NBINS - 1 ? NBINS - 1 : b0);
        b1 = b1 < 0 ? 0 : (b1 > NBINS - 1 ? NBINS - 1 : b1);
        if ((unsigned)b0 >= cutb) {
            unsigned int a = (unsigned)(2 * e);
            loc[c++] = ((unsigned long long)__float_as_uint(v.y) << 32) | (unsigned int)(~a);
        }
        if ((unsigned)b1 >= cutb) {
            unsigned int a = (unsigned)(2 * e + 1);
            loc[c++] = ((unsigned long long)__float_as_uint(v.w) << 32) | (unsigned int)(~a);
        }
    }
    unsigned int off = c ? atomicAdd(&lcnt, (unsigned)c) : 0u;
    __syncthreads();
    if (t == 0) lbase = lcnt ? atomicAdd(&cnt[b], lcnt) : 0u;
    __syncthreads();
    unsigned int gbase = lbase + off;
    for (int i = 0; i < c; ++i)
        if (gbase + i < NCAND)
            cand[(size_t)b * NCAND + gbase + i] = loc[i];
}

// ---------------- Pass 4: hybrid register/shfl/LDS bitonic sort + box decode ----------------
__device__ __forceinline__ unsigned long long shfl_xor_u64(unsigned long long v, int m) {
    int lo = __shfl_xor((int)(unsigned)(v & 0xFFFFFFFFull), m);
    int hi = __shfl_xor((int)(unsigned)(v >> 32), m);
    return ((unsigned long long)(unsigned)hi << 32) | (unsigned)lo;
}
#define SWZ(i_) ((i_) ^ (((i_) >> 3) & 7))

template<int J>
__device__ __forceinline__ void regPass(unsigned long long (&r)[8], int base, unsigned k) {
    #pragma unroll
    for (int e = 0; e < 8; ++e) {
        if ((e & J) == 0) {
            const int p = e | J;
            bool dir = (((unsigned)(base + e) & k) == 0);   // desc block
            unsigned long long lo = r[e], hi = r[p];
            bool sw = dir ? (lo < hi) : (lo > hi);
            r[e] = sw ? hi : lo;
            r[p] = sw ? lo : hi;
        }
    }
}

__device__ __forceinline__ void shflPass(unsigned long long (&r)[8], int base, int lane,
                                         unsigned k, unsigned j) {
    const int jj = (int)(j >> 3);
    const bool isHi = (lane & jj) != 0;
    #pragma unroll
    for (int e = 0; e < 8; ++e) {
        unsigned long long other = shfl_xor_u64(r[e], jj);
        bool dir = (((unsigned)(base + e) & k) == 0);
        bool takeMax = dir != isHi;
        bool gt = r[e] > other;
        r[e] = (takeMax == gt) ? r[e] : other;
    }
}

__global__ __launch_bounds__(1024) void sort_box_kernel(const unsigned long long* __restrict__ cand,
                                                        const unsigned int* __restrict__ cnt,
                                                        const float4* __restrict__ anchors,
                                                        const float4* __restrict__ bbox,
                                                        float4* __restrict__ boxesP) {
    extern __shared__ unsigned long long keys[];  // NCAND (swizzled)
    const int b = blockIdx.x;
    const int t = threadIdx.x;
    const int lane = t & 63;
    const int base = t * 8;
    unsigned int n = cnt[b]; if (n > NCAND) n = NCAND;
    const unsigned long long* cb = cand + (size_t)b * NCAND;

    unsigned long long r[8];
    #pragma unroll
    for (int e = 0; e < 8; ++e)
        r[e] = ((unsigned)(base + e) < n) ? cb[base + e] : 0ull;   // 0 sorts last (desc)

    // k = 2..512 entirely in registers + wave shuffles (no barriers)
    for (unsigned k = 2; k <= 512; k <<= 1) {
        for (unsigned j = k >> 1; j >= 8; j >>= 1) shflPass(r, base, lane, k, j);
        if (k >= 8) regPass<4>(r, base, k);
        if (k >= 4) regPass<2>(r, base, k);
        regPass<1>(r, base, k);
    }
    #pragma unroll
    for (int e = 0; e < 8; ++e) keys[SWZ(base + e)] = r[e];
    __syncthreads();

    // k = 1024..8192: LDS passes for j>=512, then shfl/reg batch
    for (unsigned k = 1024; k <= NCAND; k <<= 1) {
        for (unsigned j = k >> 1; j >= 512; j >>= 1) {
            for (int i = t; i < NCAND; i += 1024) {
                int ixj = i ^ (int)j;
                if (ixj > i) {
                    unsigned long long a0 = keys[SWZ(i)], a1 = keys[SWZ(ixj)];
                    bool dir = (((unsigned)i & k) == 0);
                    if (dir ? (a0 < a1) : (a0 > a1)) { keys[SWZ(i)] = a1; keys[SWZ(ixj)] = a0; }
                }
            }
            __syncthreads();
        }
        #pragma unroll
        for (int e = 0; e < 8; ++e) r[e] = keys[SWZ(base + e)];
        for (unsigned j = 256; j >= 8; j >>= 1) shflPass(r, base, lane, k, j);
        regPass<4>(r, base, k);
        regPass<2>(r, base, k);
        regPass<1>(r, base, k);
        #pragma unroll
        for (int e = 0; e < 8; ++e) keys[SWZ(base + e)] = r[e];
        __syncthreads();
    }

    for (int rI = t; rI < KTOP; rI += 1024) {
        unsigned long long e = keys[SWZ(rI)];
        unsigned int idx = ~(unsigned int)(e & 0xFFFFFFFFull);
        float4 anc = anchors[(size_t)b * NA + idx];
        float4 del = bbox[(size_t)b * NA + idx];
        float dy = del.x * 0.1f, dx = del.y * 0.1f, dh = del.z * 0.2f, dw = del.w * 0.2f;
        float h = anc.z - anc.x, w = anc.w - anc.y;
        float cy = anc.x + 0.5f * h + dy * h;
        float cx = anc.y + 0.5f * w + dx * w;
        h = h * expf(dh);
        w = w * expf(dw);
        float y1v = fminf(fmaxf(cy - 0.5f * h, 0.f), 1.f);
        float x1v = fminf(fmaxf(cx - 0.5f * w, 0.f), 1.f);
        float y2v = fminf(fmaxf(cy + 0.5f * h, 0.f), 1.f);
        float x2v = fminf(fmaxf(cx + 0.5f * w, 0.f), 1.f);
        boxesP[(size_t)b * NPAD + rI] = make_float4(y1v, x1v, y2v, x2v);
    }
    for (int rI = KTOP + t; rI < NPAD; rI += 1024)
        boxesP[(size_t)b * NPAD + rI] = make_float4(0.f, 0.f, 0.f, 0.f);
}

// ---------------- Pass 5a: IoU suppression sparse lists ----------------
// Row layout (8 x u16): [0]=count (filled at walk load), [1..7]=suppressed idx.
__global__ __launch_bounds__(256) void iou_kernel(const float4* __restrict__ boxesP,
                                                  unsigned int* __restrict__ rowcnt,
                                                  unsigned short* __restrict__ rowlist) {
    const int bx = blockIdx.x;          // group of 4 col chunks
    const int cy = blockIdx.y;          // row chunk
    const int b  = blockIdx.z;
    if (bx * 4 + 3 < cy) return;
    const int t  = threadIdx.x;
    __shared__ float4 cbx[256];
    __shared__ float  car[256];
    int cj = bx * 256 + t;
    float4 c4 = (cj < NPAD) ? boxesP[(size_t)b * NPAD + cj] : make_float4(0.f,0.f,0.f,0.f);
    cbx[t] = c4;
    car[t] = (c4.z - c4.x) * (c4.w - c4.y);
    __syncthreads();
    const int cx = bx * 4 + (t >> 6);
    const int tl = t & 63;
    if (cx >= MCH || cx < cy) return;
    const int i = cy * 64 + tl;
    float4 r4 = boxesP[(size_t)b * NPAD + i];
    float rar = (r4.z - r4.x) * (r4.w - r4.y);
    const int cb0 = (t >> 6) * 64;
    unsigned long long m = 0ull;
    #pragma unroll 8
    for (int j = 0; j < 64; ++j) {
        float4 q = cbx[cb0 + j];
        float yy1 = fmaxf(r4.x, q.x), xx1 = fmaxf(r4.y, q.y);
        float yy2 = fminf(r4.z, q.z), xx2 = fminf(r4.w, q.w);
        float inter = fmaxf(yy2 - yy1, 0.f) * fmaxf(xx2 - xx1, 0.f);
        float uni = rar + car[cb0 + j] - inter;
        float iou = inter / fmaxf(uni, 1e-12f);
        m |= ((unsigned long long)(iou > NMS_THR)) << j;
    }
    unsigned long long allow = (cx > cy) ? ~0ull : ((tl == 63) ? 0ull : (~0ull << (tl + 1)));
    m &= allow;
    while (m) {
        int j = __builtin_ctzll(m); m &= m - 1ull;
        int jg = cx * 64 + j;
        unsigned int pos = atomicAdd(&rowcnt[(size_t)b * NPAD + i], 1u);
        if (pos < LSLOTS)
            rowlist[((size_t)b * NPAD + i) * 8 + 1 + pos] = (unsigned short)jg;
    }
}

// ---------------- Pass 5b: batched greedy walk, wave 0 of 256-thread block ----------------
// Rows with rowcnt==0 suppress nobody -> all consecutive available zero-suppression rows
// are selected in ONE step (parallel outIdx write). Serial iterations ~ #words + #suppressing rows.
__global__ __launch_bounds__(256) void walk_kernel(const float4* __restrict__ boxesP,
                                                   const unsigned int* __restrict__ rowcnt,
                                                   const uint4* __restrict__ rowlist4,
                                                   float4* __restrict__ out) {
    extern __shared__ char smraw[];
    uint4*        rlS     = (uint4*)smraw;                           // [NPAD] = 96256 B
    unsigned int* removed = (unsigned int*)(smraw + 96256);          // 192 u32
    unsigned int* hasupS  = removed + 192;                           // 192 u32
    unsigned int* outIdx  = hasupS + 192;                            // PROP u32
    int*          selS    = (int*)(outIdx + PROP);

    const int b = blockIdx.x;
    const int t = threadIdx.x;

    if (t < 192) {
        removed[t] = (t > 187) ? 0xFFFFFFFFu : (t == 187 ? 0xFFFF0000u : 0u);
        hasupS[t] = 0u;
    }
    __syncthreads();
    const unsigned int* rc = rowcnt + (size_t)b * NPAD;
    const uint4* rl = rowlist4 + (size_t)b * NPAD;
    for (int i = t; i < NPAD; i += 256) {
        unsigned int c = rc[i];
        uint4 v = rl[i];
        v.x = (v.x & 0xFFFF0000u) | (c > 0xFFFFu ? 0xFFFFu : c);     // count in slot 0
        rlS[i] = v;
        if (c) atomicOr(&hasupS[i >> 5], 1u << (i & 31));
    }
    __syncthreads();

    if (t < 64) {
        const int lane = t;
        int w = 0, sel = 0;
        unsigned int curRem = removed[0], curHas = hasupS[0];
        while (sel < PROP) {
            unsigned int avail = ~curRem;
            if (!avail) {
                if (++w >= NW32) break;
                curRem = removed[w]; curHas = hasupS[w];
                continue;
            }
            unsigned int supp = avail & curHas;
            int fs = -1;
            unsigned int take = avail;
            if (supp) {
                fs = __ffs(supp) - 1;
                take = avail & ((2u << fs) - 1u);    // bits <= fs (fs=31 -> all)
            }
            int cnt = __popc(take);
            int need = PROP - sel;
            if (cnt > need) {
                bool keep = (lane < 32) && ((take >> lane) & 1u) &&
                            (__popc(take & ((1u << lane) - 1u)) < (unsigned)need);
                take = (unsigned int)__ballot(keep);
                cnt = need;
                if (fs >= 0 && !((take >> fs) & 1u)) fs = -1;  // fs got cut -> no list to apply
            }
            if (lane < 32 && ((take >> lane) & 1u))
                outIdx[sel + __popc(take & ((1u << lane) - 1u))] = (unsigned int)(w * 32 + lane);
            sel += cnt;
            curRem |= take;
            if (lane == 0) removed[w] = curRem;
            if (fs >= 0) {
                int i = w * 32 + fs;
                uint4 row = rlS[i];                              // broadcast LDS read
                unsigned int c = row.x & 0xFFFFu;
                if (c <= (unsigned)LSLOTS) {
                    if (lane < (int)c) {
                        unsigned int jg;
                        switch (lane) {
                            case 0: jg = row.x >> 16; break;
                            case 1: jg = row.y & 0xFFFFu; break;
                            case 2: jg = row.y >> 16; break;
                            case 3: jg = row.z & 0xFFFFu; break;
                            case 4: jg = row.z >> 16; break;
                            case 5: jg = row.w & 0xFFFFu; break;
                            default: jg = row.w >> 16; break;
                        }
                        atomicOr(&removed[jg >> 5], 1u << (jg & 31u));
                    }
                    __threadfence_block();
                    curRem = removed[w];                         // may include same-word hits
                } else {
                    // overflow (rare): recompute row i vs all j>i with 64 lanes
                    float4 bi = boxesP[(size_t)b * NPAD + i];
                    float ari = (bi.z - bi.x) * (bi.w - bi.y);
                    for (int j0 = 0; j0 < NPAD; j0 += 64) {
                        int j = j0 + lane;
                        bool sup = false;
                        if (j > i) {
                            float4 q = boxesP[(size_t)b * NPAD + j];
                            float yy1 = fmaxf(bi.x, q.x), xx1 = fmaxf(bi.y, q.y);
                            float yy2 = fminf(bi.z, q.z), xx2 = fminf(bi.w, q.w);
                            float inter = fmaxf(yy2 - yy1, 0.f) * fmaxf(xx2 - xx1, 0.f);
                            float uni = ari + (q.z - q.x) * (q.w - q.y) - inter;
                            sup = (inter / fmaxf(uni, 1e-12f)) > NMS_THR;
                        }
                        unsigned long long bal = __ballot(sup);
                        if (lane == 0 && (unsigned int)bal)
                            atomicOr(&removed[j0 >> 5], (unsigned int)bal);
                        if (lane == 1 && (unsigned int)(bal >> 32))
                            atomicOr(&removed[(j0 >> 5) + 1], (unsigned int)(bal >> 32));
                    }
                    __threadfence_block();
                    curRem = removed[w];
                }
            } else {
                if (++w >= NW32) break;
                curRem = removed[w]; curHas = hasupS[w];
            }
        }
        if (lane == 0) *selS = sel;
    }
    __syncthreads();
    int sel = *selS;
    float4* ob = out + (size_t)b * PROP;
    for (int k = t; k < PROP; k += 256) {
        float4 v = (k < sel) ? boxesP[(size_t)b * NPAD + outIdx[k]]
                             : make_float4(0.f, 0.f, 0.f, 0.f);
        ob[k] = v;
    }
}

extern "C" void kernel_launch(void* const* d_in, const int* in_sizes, int n_in,
                              void* d_out, int out_size, void* d_ws, size_t ws_size,
                              hipStream_t stream) {
    const float4* probs4  = (const float4*)d_in[0];
    const float4* bbox    = (const float4*)d_in[1];
    const float4* anchors = (const float4*)d_in[2];
    char* ws = (char*)d_ws;
    unsigned int* hist       = (unsigned int*)(ws + OFF_HIST);
    unsigned int* cnt        = (unsigned int*)(ws + OFF_CNT);
    unsigned int* rowcnt     = (unsigned int*)(ws + OFF_ROWCNT);
    unsigned int* cut        = (unsigned int*)(ws + OFF_CUT);
    unsigned long long* cand = (unsigned long long*)(ws + OFF_CAND);
    float4* boxesP           = (float4*)(ws + OFF_BOXESP);
    unsigned short* rowlist  = (unsigned short*)(ws + OFF_ROWLIST);

    hipMemsetAsync(d_ws, 0, ZERO_BYTES, stream);   // hist + cnt + rowcnt

    hist_kernel<<<dim3(NA / 8192, NBATCH), 256, 0, stream>>>(probs4, hist);
    cutoff_kernel<<<dim3(NBATCH), 64, 0, stream>>>(hist, cut);
    compact_kernel<<<dim3(NA / 4096, NBATCH), 256, 0, stream>>>(probs4, cut, cnt, cand);
    sort_box_kernel<<<dim3(NBATCH), 1024, NCAND * 8, stream>>>(cand, cnt, anchors, bbox, boxesP);
    iou_kernel<<<dim3((MCH + 3) / 4, MCH, NBATCH), 256, 0, stream>>>(boxesP, rowcnt, rowlist);
    size_t walk_lds = 96256 + 192 * 4 * 2 + PROP * 4 + 16;   // ~101.8 KB
    walk_kernel<<<dim3(NBATCH), 256, walk_lds, stream>>>(boxesP, rowcnt, (const uint4*)rowlist,
                                                         (float4*)d_out);
}

// Round 7
// 154.289 us; speedup vs baseline: 14.1722x; 1.8919x over previous
//
#include <hip/hip_runtime.h>
#include <stdint.h>

#define NBATCH 8
#define NA 262144
#define KTOP 6000
#define PROP 1000
#define NCAND 8192
#define NBINS 4096
#define NMS_THR 0.7f
#define NPAD 6016          // KTOP padded to 94*64
#define NW32 188           // ceil(6000/32)
#define LSLOTS 7           // u16 list slots per row (slot 0 = count)
#define LROWS 2048         // suppression lists computed for rows/cols < LROWS only
#define LCH 32             // LROWS/64 col-chunks
#define LW 64              // LROWS/32 u32 words

// ---- workspace layout (bytes) ----
static constexpr size_t OFF_HIST    = 0;                          // 8*4096*4 = 131072
static constexpr size_t OFF_CNT     = 131072;                     // 32
static constexpr size_t OFF_ROWCNT  = 131104;                     // 8*2048*4 = 65536
static constexpr size_t ZERO_BYTES  = 196640;                     // hist+cnt+rowcnt
static constexpr size_t OFF_CUT     = 196640;                     // 32
static constexpr size_t OFF_CAND    = 196672;                     // 8*8192*8 = 524288
static constexpr size_t OFF_BOXESP  = 720960;                     // 8*6016*16 = 770048
static constexpr size_t OFF_ROWLIST = 1491008;                    // 8*2048*8*2 = 262144

// ---------------- Pass 1: per-batch 4096-bin linear histogram (float4 loads) ----------------
__global__ __launch_bounds__(256) void hist_kernel(const float4* __restrict__ probs4,
                                                   unsigned int* __restrict__ hist) {
    __shared__ unsigned int h[NBINS];
    const int b = blockIdx.y;
    const int t = threadIdx.x;
    for (int i = t; i < NBINS; i += 256) h[i] = 0;
    __syncthreads();
    const float4* p4 = probs4 + (size_t)b * (NA / 2);
    const int base = blockIdx.x * 4096;              // float4 index (8192 anchors/block)
    for (int k = 0; k < 16; ++k) {
        float4 v = p4[base + k * 256 + t];
        int b0 = (int)(v.y * (float)NBINS);
        int b1 = (int)(v.w * (float)NBINS);
        b0 = b0 < 0 ? 0 : (b0 > NBINS - 1 ? NBINS - 1 : b0);
        b1 = b1 < 0 ? 0 : (b1 > NBINS - 1 ? NBINS - 1 : b1);
        atomicAdd(&h[b0], 1u);
        atomicAdd(&h[b1], 1u);
    }
    __syncthreads();
    unsigned int* gh = hist + (size_t)b * NBINS;
    for (int i = t; i < NBINS; i += 256) {
        unsigned int v = h[i];
        if (v) atomicAdd(&gh[i], v);
    }
}

// ---------------- Pass 2: cutoff bin, wave-parallel suffix scan ----------------
__global__ __launch_bounds__(64) void cutoff_kernel(const unsigned int* __restrict__ hist,
                                                    unsigned int* __restrict__ cut) {
    const int b = blockIdx.x;
    const int l = threadIdx.x;
    const unsigned int* h = hist + (size_t)b * NBINS;
    unsigned int s = 0;
    for (int k = 0; k < 64; ++k) s += h[l * 64 + k];
    unsigned int c = s;
    for (int off = 1; off < 64; off <<= 1) {
        unsigned int v = __shfl_down(c, off);
        if (l + off < 64) c += v;
    }
    unsigned long long ball = __ballot(c >= (unsigned)KTOP);
    int csel = 63 - __builtin_clzll(ball);
    unsigned int cnext = (csel < 63) ? __shfl(c, csel + 1) : 0u;
    unsigned int rem = (unsigned)KTOP - cnext;
    unsigned int c2 = h[csel * 64 + l];
    for (int off = 1; off < 64; off <<= 1) {
        unsigned int v = __shfl_down(c2, off);
        if (l + off < 64) c2 += v;
    }
    unsigned long long ball2 = __ballot(c2 >= rem);
    int bsel = 63 - __builtin_clzll(ball2);
    if (l == 0) cut[b] = (unsigned int)(csel * 64 + bsel);
}

// ---------------- Pass 3: compact candidates, block-aggregated atomics ----------------
__global__ __launch_bounds__(256) void compact_kernel(const float4* __restrict__ probs4,
                                                      const unsigned int* __restrict__ cut,
                                                      unsigned int* __restrict__ cnt,
                                                      unsigned long long* __restrict__ cand) {
    __shared__ unsigned int lcnt, lbase;
    const int b = blockIdx.y;
    const int t = threadIdx.x;
    const unsigned int cutb = cut[b];
    if (t == 0) lcnt = 0;
    __syncthreads();
    const float4* p4 = probs4 + (size_t)b * (NA / 2);
    const int base = blockIdx.x * 2048;              // float4 index (4096 anchors/block)
    unsigned long long loc[16];
    int c = 0;
    for (int k = 0; k < 8; ++k) {
        int e = base + k * 256 + t;
        float4 v = p4[e];
        int b0 = (int)(v.y * (float)NBINS);
        int b1 = (int)(v.w * (float)NBINS);
        b0 = b0 < 0 ? 0 : (b0 > NBINS - 1 ? NBINS - 1 : b0);
        b1 = b1 < 0 ? 0 : (b1 > NBINS - 1 ? NBINS - 1 : b1);
        if ((unsigned)b0 >= cutb) {
            unsigned int a = (unsigned)(2 * e);
            loc[c++] = ((unsigned long long)__float_as_uint(v.y) << 32) | (unsigned int)(~a);
        }
        if ((unsigned)b1 >= cutb) {
            unsigned int a = (unsigned)(2 * e + 1);
            loc[c++] = ((unsigned long long)__float_as_uint(v.w) << 32) | (unsigned int)(~a);
        }
    }
    unsigned int off = c ? atomicAdd(&lcnt, (unsigned)c) : 0u;
    __syncthreads();
    if (t == 0) lbase = lcnt ? atomicAdd(&cnt[b], lcnt) : 0u;
    __syncthreads();
    unsigned int gbase = lbase + off;
    for (int i = 0; i < c; ++i)
        if (gbase + i < NCAND)
            cand[(size_t)b * NCAND + gbase + i] = loc[i];
}

// ---------------- Pass 4: hybrid register/shfl/LDS bitonic sort + box decode ----------------
__device__ __forceinline__ unsigned long long shfl_xor_u64(unsigned long long v, int m) {
    int lo = __shfl_xor((int)(unsigned)(v & 0xFFFFFFFFull), m);
    int hi = __shfl_xor((int)(unsigned)(v >> 32), m);
    return ((unsigned long long)(unsigned)hi << 32) | (unsigned)lo;
}
#define SWZ(i_) ((i_) ^ (((i_) >> 3) & 7))

template<int J>
__device__ __forceinline__ void regPass(unsigned long long (&r)[8], int base, unsigned k) {
    #pragma unroll
    for (int e = 0; e < 8; ++e) {
        if ((e & J) == 0) {
            const int p = e | J;
            bool dir = (((unsigned)(base + e) & k) == 0);   // desc block
            unsigned long long lo = r[e], hi = r[p];
            bool sw = dir ? (lo < hi) : (lo > hi);
            r[e] = sw ? hi : lo;
            r[p] = sw ? lo : hi;
        }
    }
}

__device__ __forceinline__ void shflPass(unsigned long long (&r)[8], int base, int lane,
                                         unsigned k, unsigned j) {
    const int jj = (int)(j >> 3);
    const bool isHi = (lane & jj) != 0;
    #pragma unroll
    for (int e = 0; e < 8; ++e) {
        unsigned long long other = shfl_xor_u64(r[e], jj);
        bool dir = (((unsigned)(base + e) & k) == 0);
        bool takeMax = dir != isHi;
        bool gt = r[e] > other;
        r[e] = (takeMax == gt) ? r[e] : other;
    }
}

__global__ __launch_bounds__(1024) void sort_box_kernel(const unsigned long long* __restrict__ cand,
                                                        const unsigned int* __restrict__ cnt,
                                                        const float4* __restrict__ anchors,
                                                        const float4* __restrict__ bbox,
                                                        float4* __restrict__ boxesP) {
    extern __shared__ unsigned long long keys[];  // NCAND (swizzled)
    const int b = blockIdx.x;
    const int t = threadIdx.x;
    const int lane = t & 63;
    const int base = t * 8;
    unsigned int n = cnt[b]; if (n > NCAND) n = NCAND;
    const unsigned long long* cb = cand + (size_t)b * NCAND;

    unsigned long long r[8];
    #pragma unroll
    for (int e = 0; e < 8; ++e)
        r[e] = ((unsigned)(base + e) < n) ? cb[base + e] : 0ull;   // 0 sorts last (desc)

    // k = 2..512 entirely in registers + wave shuffles (no barriers)
    for (unsigned k = 2; k <= 512; k <<= 1) {
        for (unsigned j = k >> 1; j >= 8; j >>= 1) shflPass(r, base, lane, k, j);
        if (k >= 8) regPass<4>(r, base, k);
        if (k >= 4) regPass<2>(r, base, k);
        regPass<1>(r, base, k);
    }
    #pragma unroll
    for (int e = 0; e < 8; ++e) keys[SWZ(base + e)] = r[e];
    __syncthreads();

    // k = 1024..8192: LDS passes for j>=512, then shfl/reg batch
    for (unsigned k = 1024; k <= NCAND; k <<= 1) {
        for (unsigned j = k >> 1; j >= 512; j >>= 1) {
            for (int i = t; i < NCAND; i += 1024) {
                int ixj = i ^ (int)j;
                if (ixj > i) {
                    unsigned long long a0 = keys[SWZ(i)], a1 = keys[SWZ(ixj)];
                    bool dir = (((unsigned)i & k) == 0);
                    if (dir ? (a0 < a1) : (a0 > a1)) { keys[SWZ(i)] = a1; keys[SWZ(ixj)] = a0; }
                }
            }
            __syncthreads();
        }
        #pragma unroll
        for (int e = 0; e < 8; ++e) r[e] = keys[SWZ(base + e)];
        for (unsigned j = 256; j >= 8; j >>= 1) shflPass(r, base, lane, k, j);
        regPass<4>(r, base, k);
        regPass<2>(r, base, k);
        regPass<1>(r, base, k);
        #pragma unroll
        for (int e = 0; e < 8; ++e) keys[SWZ(base + e)] = r[e];
        __syncthreads();
    }

    for (int rI = t; rI < KTOP; rI += 1024) {
        unsigned long long e = keys[SWZ(rI)];
        unsigned int idx = ~(unsigned int)(e & 0xFFFFFFFFull);
        float4 anc = anchors[(size_t)b * NA + idx];
        float4 del = bbox[(size_t)b * NA + idx];
        float dy = del.x * 0.1f, dx = del.y * 0.1f, dh = del.z * 0.2f, dw = del.w * 0.2f;
        float h = anc.z - anc.x, w = anc.w - anc.y;
        float cy = anc.x + 0.5f * h + dy * h;
        float cx = anc.y + 0.5f * w + dx * w;
        h = h * expf(dh);
        w = w * expf(dw);
        float y1v = fminf(fmaxf(cy - 0.5f * h, 0.f), 1.f);
        float x1v = fminf(fmaxf(cx - 0.5f * w, 0.f), 1.f);
        float y2v = fminf(fmaxf(cy + 0.5f * h, 0.f), 1.f);
        float x2v = fminf(fmaxf(cx + 0.5f * w, 0.f), 1.f);
        boxesP[(size_t)b * NPAD + rI] = make_float4(y1v, x1v, y2v, x2v);
    }
    for (int rI = KTOP + t; rI < NPAD; rI += 1024)
        boxesP[(size_t)b * NPAD + rI] = make_float4(0.f, 0.f, 0.f, 0.f);
}

// ---------------- Pass 5a: IoU suppression sparse lists, [0,LROWS)^2 square only ----------------
// Row layout (8 x u16): [0]=count (filled at walk load), [1..7]=suppressed idx.
__global__ __launch_bounds__(256) void iou_kernel(const float4* __restrict__ boxesP,
                                                  unsigned int* __restrict__ rowcnt,
                                                  unsigned short* __restrict__ rowlist) {
    const int bx = blockIdx.x;          // group of 4 col chunks (LCH/4 groups)
    const int cy = blockIdx.y;          // row chunk (< LCH)
    const int b  = blockIdx.z;
    if (bx * 4 + 3 < cy) return;
    const int t  = threadIdx.x;
    __shared__ float4 cbx[256];
    __shared__ float  car[256];
    int cj = bx * 256 + t;              // < LROWS by construction
    float4 c4 = boxesP[(size_t)b * NPAD + cj];
    cbx[t] = c4;
    car[t] = (c4.z - c4.x) * (c4.w - c4.y);
    __syncthreads();
    const int cx = bx * 4 + (t >> 6);
    const int tl = t & 63;
    if (cx >= LCH || cx < cy) return;
    const int i = cy * 64 + tl;
    float4 r4 = boxesP[(size_t)b * NPAD + i];
    float rar = (r4.z - r4.x) * (r4.w - r4.y);
    const int cb0 = (t >> 6) * 64;
    unsigned long long m = 0ull;
    #pragma unroll 8
    for (int j = 0; j < 64; ++j) {
        float4 q = cbx[cb0 + j];
        float yy1 = fmaxf(r4.x, q.x), xx1 = fmaxf(r4.y, q.y);
        float yy2 = fminf(r4.z, q.z), xx2 = fminf(r4.w, q.w);
        float inter = fmaxf(yy2 - yy1, 0.f) * fmaxf(xx2 - xx1, 0.f);
        bool sup = false;
        if (inter > 0.f) {   // wave-level skip of the IEEE div when no lane overlaps
            float uni = rar + car[cb0 + j] - inter;
            sup = (inter / fmaxf(uni, 1e-12f)) > NMS_THR;
        }
        m |= ((unsigned long long)sup) << j;
    }
    unsigned long long allow = (cx > cy) ? ~0ull : ((tl == 63) ? 0ull : (~0ull << (tl + 1)));
    m &= allow;
    while (m) {
        int j = __builtin_ctzll(m); m &= m - 1ull;
        int jg = cx * 64 + j;
        unsigned int pos = atomicAdd(&rowcnt[(size_t)b * LROWS + i], 1u);
        if (pos < LSLOTS)
            rowlist[((size_t)b * LROWS + i) * 8 + 1 + pos] = (unsigned short)jg;
    }
}

// ---------------- Pass 5b: batched greedy walk, wave 0 of 256-thread block ----------------
__global__ __launch_bounds__(256) void walk_kernel(const float4* __restrict__ boxesP,
                                                   const unsigned int* __restrict__ rowcnt,
                                                   const uint4* __restrict__ rowlist4,
                                                   float4* __restrict__ out) {
    extern __shared__ char smraw[];
    uint4*        rlS     = (uint4*)smraw;                           // [LROWS] = 32768 B
    unsigned int* removed = (unsigned int*)(smraw + 32768);          // 192 u32
    unsigned int* hasupS  = removed + 192;                           // 192 u32
    unsigned int* outIdx  = hasupS + 192;                            // PROP u32
    int*          selS    = (int*)(outIdx + PROP);

    const int b = blockIdx.x;
    const int t = threadIdx.x;

    if (t < 192) {
        removed[t] = (t > 187) ? 0xFFFFFFFFu : (t == 187 ? 0xFFFF0000u : 0u);
        hasupS[t]  = (t >= LW) ? 0xFFFFFFFFu : 0u;   // rows >= LROWS: unknown -> recompute on demand
    }
    __syncthreads();
    const unsigned int* rc = rowcnt + (size_t)b * LROWS;
    const uint4* rl = rowlist4 + (size_t)b * LROWS;
    for (int i = t; i < LROWS; i += 256) {
        unsigned int c = rc[i];
        uint4 v = rl[i];
        v.x = (v.x & 0xFFFF0000u) | (c > 0xFFFFu ? 0xFFFFu : c);     // count in slot 0
        rlS[i] = v;
        if (c) atomicOr(&hasupS[i >> 5], 1u << (i & 31));
    }
    __syncthreads();

    if (t < 64) {
        const int lane = t;
        int w = 0, sel = 0;
        bool crossed = false;
        unsigned int curRem = removed[0], curHas = hasupS[0];
        while (sel < PROP) {
            if (!crossed && w >= LW) {
                // crossing LROWS: back-apply selected rows' suppressions onto cols >= LROWS
                for (int k = 0; k < sel; ++k) {
                    int s = (int)outIdx[k];
                    float4 bs = boxesP[(size_t)b * NPAD + s];
                    float ars = (bs.z - bs.x) * (bs.w - bs.y);
                    for (int j0 = LROWS; j0 < NPAD; j0 += 64) {
                        int j = j0 + lane;                           // j > s always
                        float4 q = boxesP[(size_t)b * NPAD + j];
                        float yy1 = fmaxf(bs.x, q.x), xx1 = fmaxf(bs.y, q.y);
                        float yy2 = fminf(bs.z, q.z), xx2 = fminf(bs.w, q.w);
                        float inter = fmaxf(yy2 - yy1, 0.f) * fmaxf(xx2 - xx1, 0.f);
                        float uni = ars + (q.z - q.x) * (q.w - q.y) - inter;
                        bool sup = (inter / fmaxf(uni, 1e-12f)) > NMS_THR;
                        unsigned long long bal = __ballot(sup);
                        if (lane == 0 && (unsigned int)bal)
                            atomicOr(&removed[j0 >> 5], (unsigned int)bal);
                        if (lane == 1 && (unsigned int)(bal >> 32))
                            atomicOr(&removed[(j0 >> 5) + 1], (unsigned int)(bal >> 32));
                    }
                }
                __threadfence_block();
                crossed = true;
                curRem = removed[w]; curHas = hasupS[w];
                continue;
            }
            unsigned int avail = ~curRem;
            if (!avail) {
                if (++w >= NW32) break;
                curRem = removed[w]; curHas = hasupS[w];
                continue;
            }
            unsigned int supp = avail & curHas;
            int fs = -1;
            unsigned int take = avail;
            if (supp) {
                fs = __ffs(supp) - 1;
                take = avail & ((2u << fs) - 1u);    // bits <= fs (fs=31 -> all)
            }
            int cnt = __popc(take);
            int need = PROP - sel;
            if (cnt > need) {
                bool keep = (lane < 32) && ((take >> lane) & 1u) &&
                            (__popc(take & ((1u << lane) - 1u)) < (unsigned)need);
                take = (unsigned int)__ballot(keep);
                cnt = need;
                if (fs >= 0 && !((take >> fs) & 1u)) fs = -1;  // fs got cut -> no list to apply
            }
            if (lane < 32 && ((take >> lane) & 1u))
                outIdx[sel + __popc(take & ((1u << lane) - 1u))] = (unsigned int)(w * 32 + lane);
            sel += cnt;
            curRem |= take;
            if (lane == 0) removed[w] = curRem;
            if (fs >= 0) {
                int i = w * 32 + fs;
                bool needFull = true;
                if (i < LROWS) {
                    uint4 row = rlS[i];                          // broadcast LDS read
                    unsigned int c = row.x & 0xFFFFu;
                    if (c <= (unsigned)LSLOTS) {
                        needFull = false;
                        if (lane < (int)c) {
                            unsigned int jg;
                            switch (lane) {
                                case 0: jg = row.x >> 16; break;
                                case 1: jg = row.y & 0xFFFFu; break;
                                case 2: jg = row.y >> 16; break;
                                case 3: jg = row.z & 0xFFFFu; break;
                                case 4: jg = row.z >> 16; break;
                                case 5: jg = row.w & 0xFFFFu; break;
                                default: jg = row.w >> 16; break;
                            }
                            atomicOr(&removed[jg >> 5], 1u << (jg & 31u));
                        }
                        __threadfence_block();
                        curRem = removed[w];                     // may include same-word hits
                    }
                }
                if (needFull) {
                    // overflow or row >= LROWS: recompute row i vs all j > i with 64 lanes
                    float4 bi = boxesP[(size_t)b * NPAD + i];
                    float ari = (bi.z - bi.x) * (bi.w - bi.y);
                    for (int j0 = 0; j0 < NPAD; j0 += 64) {
                        int j = j0 + lane;
                        bool sup = false;
                        if (j > i) {
                            float4 q = boxesP[(size_t)b * NPAD + j];
                            float yy1 = fmaxf(bi.x, q.x), xx1 = fmaxf(bi.y, q.y);
                            float yy2 = fminf(bi.z, q.z), xx2 = fminf(bi.w, q.w);
                            float inter = fmaxf(yy2 - yy1, 0.f) * fmaxf(xx2 - xx1, 0.f);
                            float uni = ari + (q.z - q.x) * (q.w - q.y) - inter;
                            sup = (inter / fmaxf(uni, 1e-12f)) > NMS_THR;
                        }
                        unsigned long long bal = __ballot(sup);
                        if (lane == 0 && (unsigned int)bal)
                            atomicOr(&removed[j0 >> 5], (unsigned int)bal);
                        if (lane == 1 && (unsigned int)(bal >> 32))
                            atomicOr(&removed[(j0 >> 5) + 1], (unsigned int)(bal >> 32));
                    }
                    __threadfence_block();
                    curRem = removed[w];
                }
            } else {
                if (++w >= NW32) break;
                curRem = removed[w]; curHas = hasupS[w];
            }
        }
        if (lane == 0) *selS = sel;
    }
    __syncthreads();
    int sel = *selS;
    float4* ob = out + (size_t)b * PROP;
    for (int k = t; k < PROP; k += 256) {
        float4 v = (k < sel) ? boxesP[(size_t)b * NPAD + outIdx[k]]
                             : make_float4(0.f, 0.f, 0.f, 0.f);
        ob[k] = v;
    }
}

extern "C" void kernel_launch(void* const* d_in, const int* in_sizes, int n_in,
                              void* d_out, int out_size, void* d_ws, size_t ws_size,
                              hipStream_t stream) {
    const float4* probs4  = (const float4*)d_in[0];
    const float4* bbox    = (const float4*)d_in[1];
    const float4* anchors = (const float4*)d_in[2];
    char* ws = (char*)d_ws;
    unsigned int* hist       = (unsigned int*)(ws + OFF_HIST);
    unsigned int* cnt        = (unsigned int*)(ws + OFF_CNT);
    unsigned int* rowcnt     = (unsigned int*)(ws + OFF_ROWCNT);
    unsigned int* cut        = (unsigned int*)(ws + OFF_CUT);
    unsigned long long* cand = (unsigned long long*)(ws + OFF_CAND);
    float4* boxesP           = (float4*)(ws + OFF_BOXESP);
    unsigned short* rowlist  = (unsigned short*)(ws + OFF_ROWLIST);

    hipMemsetAsync(d_ws, 0, ZERO_BYTES, stream);   // hist + cnt + rowcnt

    hist_kernel<<<dim3(NA / 8192, NBATCH), 256, 0, stream>>>(probs4, hist);
    cutoff_kernel<<<dim3(NBATCH), 64, 0, stream>>>(hist, cut);
    compact_kernel<<<dim3(NA / 4096, NBATCH), 256, 0, stream>>>(probs4, cut, cnt, cand);
    sort_box_kernel<<<dim3(NBATCH), 1024, NCAND * 8, stream>>>(cand, cnt, anchors, bbox, boxesP);
    iou_kernel<<<dim3(LCH / 4, LCH, NBATCH), 256, 0, stream>>>(boxesP, rowcnt, rowlist);
    size_t walk_lds = 32768 + 192 * 4 * 2 + PROP * 4 + 16;   // ~38.3 KB
    walk_kernel<<<dim3(NBATCH), 256, walk_lds, stream>>>(boxesP, rowcnt, (const uint4*)rowlist,
                                                         (float4*)d_out);
}

// Round 8
// 130.515 us; speedup vs baseline: 16.7537x; 1.1822x over previous
//
#include <hip/hip_runtime.h>
#include <stdint.h>

#define NBATCH 8
#define NA 262144
#define KTOP 6000
#define PROP 1000
#define NCAND 8192         // per-batch sorted-candidate segment capacity
#define NBINS 4096
#define NMS_THR 0.7f
#define NPAD 6016          // KTOP padded to 94*64
#define NW32 188           // ceil(6000/32)
#define LSLOTS 7           // u16 list slots per row (slot 0 = count)
#define LROWS 2048         // suppression lists computed for rows/cols < LROWS only
#define LCH 32             // LROWS/64 col-chunks
#define LW 64              // LROWS/32 u32 words

// ---- workspace layout (bytes) ----
static constexpr size_t OFF_HIST    = 0;                          // 8*4096*4 = 131072
static constexpr size_t OFF_BINPOS  = 131072;                     // 8*4096*4 = 131072
static constexpr size_t OFF_ROWCNT  = 262144;                     // 8*2048*4 = 65536
static constexpr size_t ZERO_BYTES  = 327680;                     // hist+binpos+rowcnt
static constexpr size_t OFF_CUT     = 327680;                     // 32
static constexpr size_t OFF_BINBASE = 327712;                     // 8*4096*4 = 131072
static constexpr size_t OFF_CAND    = 458784;                     // 8*8192*8 = 524288
static constexpr size_t OFF_BOXESP  = 983072;                     // 8*6016*16 = 770048
static constexpr size_t OFF_ROWLIST = 1753120;                    // 8*2048*8*2 = 262144

// ---------------- Pass 1: per-batch 4096-bin linear histogram (float4 loads) ----------------
__global__ __launch_bounds__(256) void hist_kernel(const float4* __restrict__ probs4,
                                                   unsigned int* __restrict__ hist) {
    __shared__ unsigned int h[NBINS];
    const int b = blockIdx.y;
    const int t = threadIdx.x;
    for (int i = t; i < NBINS; i += 256) h[i] = 0;
    __syncthreads();
    const float4* p4 = probs4 + (size_t)b * (NA / 2);
    const int base = blockIdx.x * 4096;              // float4 index (8192 anchors/block)
    for (int k = 0; k < 16; ++k) {
        float4 v = p4[base + k * 256 + t];
        int b0 = (int)(v.y * (float)NBINS);
        int b1 = (int)(v.w * (float)NBINS);
        b0 = b0 < 0 ? 0 : (b0 > NBINS - 1 ? NBINS - 1 : b0);
        b1 = b1 < 0 ? 0 : (b1 > NBINS - 1 ? NBINS - 1 : b1);
        atomicAdd(&h[b0], 1u);
        atomicAdd(&h[b1], 1u);
    }
    __syncthreads();
    unsigned int* gh = hist + (size_t)b * NBINS;
    for (int i = t; i < NBINS; i += 256) {
        unsigned int v = h[i];
        if (v) atomicAdd(&gh[i], v);
    }
}

// ---------------- Pass 2: cutoff bin, wave-parallel suffix scan ----------------
__global__ __launch_bounds__(64) void cutoff_kernel(const unsigned int* __restrict__ hist,
                                                    unsigned int* __restrict__ cut) {
    const int b = blockIdx.x;
    const int l = threadIdx.x;
    const unsigned int* h = hist + (size_t)b * NBINS;
    unsigned int s = 0;
    for (int k = 0; k < 64; ++k) s += h[l * 64 + k];
    unsigned int c = s;
    for (int off = 1; off < 64; off <<= 1) {
        unsigned int v = __shfl_down(c, off);
        if (l + off < 64) c += v;
    }
    unsigned long long ball = __ballot(c >= (unsigned)KTOP);
    int csel = 63 - __builtin_clzll(ball);
    unsigned int cnext = (csel < 63) ? __shfl(c, csel + 1) : 0u;
    unsigned int rem = (unsigned)KTOP - cnext;
    unsigned int c2 = h[csel * 64 + l];
    for (int off = 1; off < 64; off <<= 1) {
        unsigned int v = __shfl_down(c2, off);
        if (l + off < 64) c2 += v;
    }
    unsigned long long ball2 = __ballot(c2 >= rem);
    int bsel = 63 - __builtin_clzll(ball2);
    if (l == 0) cut[b] = (unsigned int)(csel * 64 + bsel);
}

// ---------------- Pass 2b: per-bin output bases = suffix sum from top bin ----------------
__global__ __launch_bounds__(1024) void binscan_kernel(const unsigned int* __restrict__ hist,
                                                       unsigned int* __restrict__ binbase) {
    const int b = blockIdx.x;
    const int t = threadIdx.x;
    const unsigned int* h = hist + (size_t)b * NBINS;
    unsigned int* bb = binbase + (size_t)b * NBINS;
    const int bin0 = NBINS - 4 * t - 4;              // chunk t owns 4 bins, descending chunks
    const unsigned int c0 = h[bin0 + 3], c1 = h[bin0 + 2], c2 = h[bin0 + 1], c3 = h[bin0];
    const unsigned int csum = c0 + c1 + c2 + c3;
    const int lane = t & 63, wid = t >> 6;
    unsigned int x = csum;                            // inclusive wave scan
    for (int off = 1; off < 64; off <<= 1) {
        unsigned int v = __shfl_up(x, off);
        if (lane >= off) x += v;
    }
    __shared__ unsigned int wsum[16], woff[16];
    if (lane == 63) wsum[wid] = x;
    __syncthreads();
    if (t == 0) { unsigned int acc = 0; for (int i = 0; i < 16; ++i) { woff[i] = acc; acc += wsum[i]; } }
    __syncthreads();
    unsigned int excl = x - csum + woff[wid];
    bb[bin0 + 3] = excl; excl += c0;
    bb[bin0 + 2] = excl; excl += c1;
    bb[bin0 + 1] = excl; excl += c2;
    bb[bin0]     = excl;
}

// ---------------- Pass 3: compact + counting-sort scatter into bin segments ----------------
__global__ __launch_bounds__(256) void compact_kernel(const float4* __restrict__ probs4,
                                                      const unsigned int* __restrict__ cut,
                                                      const unsigned int* __restrict__ binbase,
                                                      unsigned int* __restrict__ binpos,
                                                      unsigned long long* __restrict__ cand) {
    const int b = blockIdx.y;
    const int t = threadIdx.x;
    const unsigned int cutb = cut[b];
    const unsigned int* bb = binbase + (size_t)b * NBINS;
    unsigned int* bp = binpos + (size_t)b * NBINS;
    unsigned long long* cd = cand + (size_t)b * NCAND;
    const float4* p4 = probs4 + (size_t)b * (NA / 2);
    const int base = blockIdx.x * 2048;              // float4 index (4096 anchors/block)
    for (int k = 0; k < 8; ++k) {
        int e = base + k * 256 + t;
        float4 v = p4[e];
        int b0 = (int)(v.y * (float)NBINS);
        int b1 = (int)(v.w * (float)NBINS);
        b0 = b0 < 0 ? 0 : (b0 > NBINS - 1 ? NBINS - 1 : b0);
        b1 = b1 < 0 ? 0 : (b1 > NBINS - 1 ? NBINS - 1 : b1);
        if ((unsigned)b0 >= cutb) {
            unsigned int a = (unsigned)(2 * e);
            unsigned int slot = bb[b0] + atomicAdd(&bp[b0], 1u);
            if (slot < NCAND)
                cd[slot] = ((unsigned long long)__float_as_uint(v.y) << 32) | (unsigned int)(~a);
        }
        if ((unsigned)b1 >= cutb) {
            unsigned int a = (unsigned)(2 * e + 1);
            unsigned int slot = bb[b1] + atomicAdd(&bp[b1], 1u);
            if (slot < NCAND)
                cd[slot] = ((unsigned long long)__float_as_uint(v.w) << 32) | (unsigned int)(~a);
        }
    }
}

// ---------------- Pass 4a: per-bin register/shuffle bitonic sort (1 wave / bin) ----------------
__device__ __forceinline__ unsigned long long shfl_xor_u64(unsigned long long v, int m) {
    int lo = __shfl_xor((int)(unsigned)(v & 0xFFFFFFFFull), m);
    int hi = __shfl_xor((int)(unsigned)(v >> 32), m);
    return ((unsigned long long)(unsigned)hi << 32) | (unsigned)lo;
}

template<int J>
__device__ __forceinline__ void regPass(unsigned long long (&r)[8], int base, unsigned k) {
    #pragma unroll
    for (int e = 0; e < 8; ++e) {
        if ((e & J) == 0) {
            const int p = e | J;
            bool dir = (((unsigned)(base + e) & k) == 0);   // desc block
            unsigned long long lo = r[e], hi = r[p];
            bool sw = dir ? (lo < hi) : (lo > hi);
            r[e] = sw ? hi : lo;
            r[p] = sw ? lo : hi;
        }
    }
}

__device__ __forceinline__ void shflPass(unsigned long long (&r)[8], int base, int lane,
                                         unsigned k, unsigned j) {
    const int jj = (int)(j >> 3);
    const bool isHi = (lane & jj) != 0;
    #pragma unroll
    for (int e = 0; e < 8; ++e) {
        unsigned long long other = shfl_xor_u64(r[e], jj);
        bool dir = (((unsigned)(base + e) & k) == 0);
        bool takeMax = dir != isHi;
        bool gt = r[e] > other;
        r[e] = (takeMax == gt) ? r[e] : other;
    }
}

__global__ __launch_bounds__(256) void binsort_kernel(const unsigned int* __restrict__ binbase,
                                                      const unsigned int* __restrict__ binpos,
                                                      unsigned long long* __restrict__ cand) {
    const int b = blockIdx.y;
    const int bin = blockIdx.x * 4 + (threadIdx.x >> 6);
    const int lane = threadIdx.x & 63;
    unsigned int n = binpos[(size_t)b * NBINS + bin];
    if (n == 0) return;
    unsigned int base = binbase[(size_t)b * NBINS + bin];
    if (base >= NCAND) return;
    if (n > NCAND - base) n = NCAND - base;
    if (n > 512) n = 512;                            // statistically impossible (Poisson ~64)
    unsigned long long* seg = cand + (size_t)b * NCAND + base;
    const int vbase = lane * 8;
    unsigned long long r[8];
    #pragma unroll
    for (int e = 0; e < 8; ++e)
        r[e] = ((unsigned)(vbase + e) < n) ? seg[vbase + e] : 0ull;   // 0 sorts last (desc)
    for (unsigned k = 2; k <= 512; k <<= 1) {
        for (unsigned j = k >> 1; j >= 8; j >>= 1) shflPass(r, vbase, lane, k, j);
        if (k >= 8) regPass<4>(r, vbase, k);
        if (k >= 4) regPass<2>(r, vbase, k);
        regPass<1>(r, vbase, k);
    }
    #pragma unroll
    for (int e = 0; e < 8; ++e)
        if ((unsigned)(vbase + e) < n) seg[vbase + e] = r[e];
}

// ---------------- Pass 4b: gather + box decode (fully parallel) ----------------
__global__ __launch_bounds__(256) void decode_kernel(const unsigned long long* __restrict__ cand,
                                                     const float4* __restrict__ anchors,
                                                     const float4* __restrict__ bbox,
                                                     float4* __restrict__ boxesP) {
    const int b = blockIdx.y;
    const int rI = blockIdx.x * 256 + threadIdx.x;
    if (rI >= NPAD) return;
    if (rI < KTOP) {
        unsigned long long e = cand[(size_t)b * NCAND + rI];
        unsigned int idx = ~(unsigned int)(e & 0xFFFFFFFFull);
        float4 anc = anchors[(size_t)b * NA + idx];
        float4 del = bbox[(size_t)b * NA + idx];
        float dy = del.x * 0.1f, dx = del.y * 0.1f, dh = del.z * 0.2f, dw = del.w * 0.2f;
        float h = anc.z - anc.x, w = anc.w - anc.y;
        float cy = anc.x + 0.5f * h + dy * h;
        float cx = anc.y + 0.5f * w + dx * w;
        h = h * expf(dh);
        w = w * expf(dw);
        float y1v = fminf(fmaxf(cy - 0.5f * h, 0.f), 1.f);
        float x1v = fminf(fmaxf(cx - 0.5f * w, 0.f), 1.f);
        float y2v = fminf(fmaxf(cy + 0.5f * h, 0.f), 1.f);
        float x2v = fminf(fmaxf(cx + 0.5f * w, 0.f), 1.f);
        boxesP[(size_t)b * NPAD + rI] = make_float4(y1v, x1v, y2v, x2v);
    } else {
        boxesP[(size_t)b * NPAD + rI] = make_float4(0.f, 0.f, 0.f, 0.f);
    }
}

// ---------------- Pass 5a: IoU suppression sparse lists, [0,LROWS)^2 square only ----------------
__global__ __launch_bounds__(256) void iou_kernel(const float4* __restrict__ boxesP,
                                                  unsigned int* __restrict__ rowcnt,
                                                  unsigned short* __restrict__ rowlist) {
    const int bx = blockIdx.x;          // group of 4 col chunks (LCH/4 groups)
    const int cy = blockIdx.y;          // row chunk (< LCH)
    const int b  = blockIdx.z;
    if (bx * 4 + 3 < cy) return;
    const int t  = threadIdx.x;
    __shared__ float4 cbx[256];
    __shared__ float  car[256];
    int cj = bx * 256 + t;              // < LROWS by construction
    float4 c4 = boxesP[(size_t)b * NPAD + cj];
    cbx[t] = c4;
    car[t] = (c4.z - c4.x) * (c4.w - c4.y);
    __syncthreads();
    const int cx = bx * 4 + (t >> 6);
    const int tl = t & 63;
    if (cx >= LCH || cx < cy) return;
    const int i = cy * 64 + tl;
    float4 r4 = boxesP[(size_t)b * NPAD + i];
    float rar = (r4.z - r4.x) * (r4.w - r4.y);
    const int cb0 = (t >> 6) * 64;
    unsigned long long m = 0ull;
    #pragma unroll 8
    for (int j = 0; j < 64; ++j) {
        float4 q = cbx[cb0 + j];
        float yy1 = fmaxf(r4.x, q.x), xx1 = fmaxf(r4.y, q.y);
        float yy2 = fminf(r4.z, q.z), xx2 = fminf(r4.w, q.w);
        float inter = fmaxf(yy2 - yy1, 0.f) * fmaxf(xx2 - xx1, 0.f);
        bool sup = false;
        if (inter > 0.f) {   // wave-level skip of the IEEE div when no lane overlaps
            float uni = rar + car[cb0 + j] - inter;
            sup = (inter / fmaxf(uni, 1e-12f)) > NMS_THR;
        }
        m |= ((unsigned long long)sup) << j;
    }
    unsigned long long allow = (cx > cy) ? ~0ull : ((tl == 63) ? 0ull : (~0ull << (tl + 1)));
    m &= allow;
    while (m) {
        int j = __builtin_ctzll(m); m &= m - 1ull;
        int jg = cx * 64 + j;
        unsigned int pos = atomicAdd(&rowcnt[(size_t)b * LROWS + i], 1u);
        if (pos < LSLOTS)
            rowlist[((size_t)b * LROWS + i) * 8 + 1 + pos] = (unsigned short)jg;
    }
}

// ---------------- Pass 5b: batched greedy walk, wave 0 of 256-thread block ----------------
__global__ __launch_bounds__(256) void walk_kernel(const float4* __restrict__ boxesP,
                                                   const unsigned int* __restrict__ rowcnt,
                                                   const uint4* __restrict__ rowlist4,
                                                   float4* __restrict__ out) {
    extern __shared__ char smraw[];
    uint4*        rlS     = (uint4*)smraw;                           // [LROWS] = 32768 B
    unsigned int* removed = (unsigned int*)(smraw + 32768);          // 192 u32
    unsigned int* hasupS  = removed + 192;                           // 192 u32
    unsigned int* outIdx  = hasupS + 192;                            // PROP u32
    int*          selS    = (int*)(outIdx + PROP);

    const int b = blockIdx.x;
    const int t = threadIdx.x;

    if (t < 192) {
        removed[t] = (t > 187) ? 0xFFFFFFFFu : (t == 187 ? 0xFFFF0000u : 0u);
        hasupS[t]  = (t >= LW) ? 0xFFFFFFFFu : 0u;   // rows >= LROWS: unknown -> recompute on demand
    }
    __syncthreads();
    const unsigned int* rc = rowcnt + (size_t)b * LROWS;
    const uint4* rl = rowlist4 + (size_t)b * LROWS;
    for (int i = t; i < LROWS; i += 256) {
        unsigned int c = rc[i];
        uint4 v = rl[i];
        v.x = (v.x & 0xFFFF0000u) | (c > 0xFFFFu ? 0xFFFFu : c);     // count in slot 0
        rlS[i] = v;
        if (c) atomicOr(&hasupS[i >> 5], 1u << (i & 31));
    }
    __syncthreads();

    if (t < 64) {
        const int lane = t;
        int w = 0, sel = 0;
        bool crossed = false;
        unsigned int curRem = removed[0], curHas = hasupS[0];
        while (sel < PROP) {
            if (!crossed && w >= LW) {
                // crossing LROWS: back-apply selected rows' suppressions onto cols >= LROWS
                for (int k = 0; k < sel; ++k) {
                    int s = (int)outIdx[k];
                    float4 bs = boxesP[(size_t)b * NPAD + s];
                    float ars = (bs.z - bs.x) * (bs.w - bs.y);
                    for (int j0 = LROWS; j0 < NPAD; j0 += 64) {
                        int j = j0 + lane;                           // j > s always
                        float4 q = boxesP[(size_t)b * NPAD + j];
                        float yy1 = fmaxf(bs.x, q.x), xx1 = fmaxf(bs.y, q.y);
                        float yy2 = fminf(bs.z, q.z), xx2 = fminf(bs.w, q.w);
                        float inter = fmaxf(yy2 - yy1, 0.f) * fmaxf(xx2 - xx1, 0.f);
                        float uni = ars + (q.z - q.x) * (q.w - q.y) - inter;
                        bool sup = (inter / fmaxf(uni, 1e-12f)) > NMS_THR;
                        unsigned long long bal = __ballot(sup);
                        if (lane == 0 && (unsigned int)bal)
                            atomicOr(&removed[j0 >> 5], (unsigned int)bal);
                        if (lane == 1 && (unsigned int)(bal >> 32))
                            atomicOr(&removed[(j0 >> 5) + 1], (unsigned int)(bal >> 32));
                    }
                }
                __threadfence_block();
                crossed = true;
                curRem = removed[w]; curHas = hasupS[w];
                continue;
            }
            unsigned int avail = ~curRem;
            if (!avail) {
                if (++w >= NW32) break;
                curRem = removed[w]; curHas = hasupS[w];
                continue;
            }
            unsigned int supp = avail & curHas;
            int fs = -1;
            unsigned int take = avail;
            if (supp) {
                fs = __ffs(supp) - 1;
                take = avail & ((2u << fs) - 1u);    // bits <= fs (fs=31 -> all)
            }
            int cnt = __popc(take);
            int need = PROP - sel;
            if (cnt > need) {
                bool keep = (lane < 32) && ((take >> lane) & 1u) &&
                            (__popc(take & ((1u << lane) - 1u)) < (unsigned)need);
                take = (unsigned int)__ballot(keep);
                cnt = need;
                if (fs >= 0 && !((take >> fs) & 1u)) fs = -1;  // fs got cut -> no list to apply
            }
            if (lane < 32 && ((take >> lane) & 1u))
                outIdx[sel + __popc(take & ((1u << lane) - 1u))] = (unsigned int)(w * 32 + lane);
            sel += cnt;
            curRem |= take;
            if (lane == 0) removed[w] = curRem;
            if (fs >= 0) {
                int i = w * 32 + fs;
                bool needFull = true;
                if (i < LROWS) {
                    uint4 row = rlS[i];                          // broadcast LDS read
                    unsigned int c = row.x & 0xFFFFu;
                    if (c <= (unsigned)LSLOTS) {
                        needFull = false;
                        if (lane < (int)c) {
                            unsigned int jg;
                            switch (lane) {
                                case 0: jg = row.x >> 16; break;
                                case 1: jg = row.y & 0xFFFFu; break;
                                case 2: jg = row.y >> 16; break;
                                case 3: jg = row.z & 0xFFFFu; break;
                                case 4: jg = row.z >> 16; break;
                                case 5: jg = row.w & 0xFFFFu; break;
                                default: jg = row.w >> 16; break;
                            }
                            atomicOr(&removed[jg >> 5], 1u << (jg & 31u));
                        }
                        __threadfence_block();
                        curRem = removed[w];                     // may include same-word hits
                    }
                }
                if (needFull) {
                    // overflow or row >= LROWS: recompute row i vs all j > i with 64 lanes
                    float4 bi = boxesP[(size_t)b * NPAD + i];
                    float ari = (bi.z - bi.x) * (bi.w - bi.y);
                    for (int j0 = 0; j0 < NPAD; j0 += 64) {
                        int j = j0 + lane;
                        bool sup = false;
                        if (j > i) {
                            float4 q = boxesP[(size_t)b * NPAD + j];
                            float yy1 = fmaxf(bi.x, q.x), xx1 = fmaxf(bi.y, q.y);
                            float yy2 = fminf(bi.z, q.z), xx2 = fminf(bi.w, q.w);
                            float inter = fmaxf(yy2 - yy1, 0.f) * fmaxf(xx2 - xx1, 0.f);
                            float uni = ari + (q.z - q.x) * (q.w - q.y) - inter;
                            sup = (inter / fmaxf(uni, 1e-12f)) > NMS_THR;
                        }
                        unsigned long long bal = __ballot(sup);
                        if (lane == 0 && (unsigned int)bal)
                            atomicOr(&removed[j0 >> 5], (unsigned int)bal);
                        if (lane == 1 && (unsigned int)(bal >> 32))
                            atomicOr(&removed[(j0 >> 5) + 1], (unsigned int)(bal >> 32));
                    }
                    __threadfence_block();
                    curRem = removed[w];
                }
            } else {
                if (++w >= NW32) break;
                curRem = removed[w]; curHas = hasupS[w];
            }
        }
        if (lane == 0) *selS = sel;
    }
    __syncthreads();
    int sel = *selS;
    float4* ob = out + (size_t)b * PROP;
    for (int k = t; k < PROP; k += 256) {
        float4 v = (k < sel) ? boxesP[(size_t)b * NPAD + outIdx[k]]
                             : make_float4(0.f, 0.f, 0.f, 0.f);
        ob[k] = v;
    }
}

extern "C" void kernel_launch(void* const* d_in, const int* in_sizes, int n_in,
                              void* d_out, int out_size, void* d_ws, size_t ws_size,
                              hipStream_t stream) {
    const float4* probs4  = (const float4*)d_in[0];
    const float4* bbox    = (const float4*)d_in[1];
    const float4* anchors = (const float4*)d_in[2];
    char* ws = (char*)d_ws;
    unsigned int* hist       = (unsigned int*)(ws + OFF_HIST);
    unsigned int* binpos     = (unsigned int*)(ws + OFF_BINPOS);
    unsigned int* rowcnt     = (unsigned int*)(ws + OFF_ROWCNT);
    unsigned int* cut        = (unsigned int*)(ws + OFF_CUT);
    unsigned int* binbase    = (unsigned int*)(ws + OFF_BINBASE);
    unsigned long long* cand = (unsigned long long*)(ws + OFF_CAND);
    float4* boxesP           = (float4*)(ws + OFF_BOXESP);
    unsigned short* rowlist  = (unsigned short*)(ws + OFF_ROWLIST);

    hipMemsetAsync(d_ws, 0, ZERO_BYTES, stream);   // hist + binpos + rowcnt

    hist_kernel<<<dim3(NA / 8192, NBATCH), 256, 0, stream>>>(probs4, hist);
    cutoff_kernel<<<dim3(NBATCH), 64, 0, stream>>>(hist, cut);
    binscan_kernel<<<dim3(NBATCH), 1024, 0, stream>>>(hist, binbase);
    compact_kernel<<<dim3(NA / 4096, NBATCH), 256, 0, stream>>>(probs4, cut, binbase, binpos, cand);
    binsort_kernel<<<dim3(NBINS / 4, NBATCH), 256, 0, stream>>>(binbase, binpos, cand);
    decode_kernel<<<dim3((NPAD + 255) / 256, NBATCH), 256, 0, stream>>>(cand, anchors, bbox, boxesP);
    iou_kernel<<<dim3(LCH / 4, LCH, NBATCH), 256, 0, stream>>>(boxesP, rowcnt, rowlist);
    size_t walk_lds = 32768 + 192 * 4 * 2 + PROP * 4 + 16;   // ~38.3 KB
    walk_kernel<<<dim3(NBATCH), 256, walk_lds, stream>>>(boxesP, rowcnt, (const uint4*)rowlist,
                                                         (float4*)d_out);
}